// Round 7
// baseline (650.812 us; speedup 1.0000x reference)
//
#include <hip/hip_runtime.h>

#define N_INST   1000000
#define NBX      512
#define NBY      512
#define NB       (NBX * NBY)
#define NUM_CKSR 48
#define NUM_CE   96
#define K        4          // w[4] of the reference 5-tap is identically 0 (half = 1.5 exactly)

// FF tiling: 16x8-bin tiles, dilated bucketing (4-bin footprint straddles <= 2x2 tiles).
#define FTX   16
#define FTY   8
#define TGX   (NBX / FTX)   // 32
#define TGY   (NBY / FTY)   // 64
#define NFT   (TGX * TGY)   // 2048
#define FCAP  256           // mean ~114/tile (dup factor 1.633), 13 sigma headroom
#define RS    145           // LDS row stride: 144 channels + 1 (odd -> conflict-free)

#define CSTRIDE 16          // one bucket cursor per 64B line (R5: kills line-atomic serialization)

// Constants folded in DOUBLE then rounded once to f32 (matches JAX): half = 1.5f exactly.
#define KHALF  ((float)(2.5 * 0.6))
#define KDENOM ((float)(0.6 * 1.4142135623730951))

// 4-tap truncated-Gaussian weights. Shared erf edges (hi_c[k] == lo_c[k+1] are the same
// fp expression in the reference) -> 5 phis, bit-identical to the reference's 10-phi form;
// w[4] == 0.0 exactly and is dropped. When w[k] != 0 the bin lo+k is in [0, nbins).
__device__ __forceinline__ void axis_weights4(float pos, int nbins, int& lo_out, float w[K]) {
    float wlo = pos - KHALF;
    float whi = pos + KHALF;
    int lo_bin = (int)floorf(wlo);
    lo_out = lo_bin;
    float phi[K + 1];
#pragma unroll
    for (int k = 0; k <= K; ++k) {
        float e = (float)(lo_bin + k);
        float ec = fminf(fmaxf(e, wlo), whi);
        phi[k] = 0.5f * (1.f + erff((ec - pos) / KDENOM));
    }
    float wsum = 0.f;
#pragma unroll
    for (int k = 0; k < K; ++k) {
        int b = lo_bin + k;
        float ww = phi[k + 1] - phi[k];
        if (b < 0 || b >= nbins) ww = 0.f;
        w[k] = ww;
        wsum += ww;
    }
    float d = wsum + 1e-12f;
#pragma unroll
    for (int k = 0; k < K; ++k) w[k] = w[k] / d;   // division, as in reference
}

// Pass 1: lut -> 16 direct fire-and-forget atomics into lut_dem (~700 same-line ops/line,
// ~11us drain per R4's calibrated per-line model); ff -> dilated 16x8-tile buckets.
__global__ void __launch_bounds__(256) classify_kernel(
        const float* __restrict__ pos,
        const int* __restrict__ luts,
        const int* __restrict__ ffs,
        const int* __restrict__ ctrl,
        float* __restrict__ lut_dem,       // [NB] zeroed
        int* __restrict__ ff_counts,       // [NFT*CSTRIDE] zeroed
        uint4* __restrict__ ff_buckets) {  // [NFT][FCAP]
    int i = blockIdx.x * blockDim.x + threadIdx.x;
    if (i >= N_INST) return;
    float px = pos[2 * i], py = pos[2 * i + 1];

    if (luts[i] > 0) {
        int lox, loy;
        float wx[K], wy[K];
        axis_weights4(px, NBX, lox, wx);
        axis_weights4(py, NBY, loy, wy);
#pragma unroll
        for (int kx = 0; kx < K; ++kx) {
            if (wx[kx] == 0.f) continue;
#pragma unroll
            for (int ky = 0; ky < K; ++ky) {
                float w2 = wx[kx] * wy[ky];
                if (w2 != 0.f)
                    unsafeAtomicAdd(&lut_dem[(lox + kx) * NBY + (loy + ky)], w2);
            }
        }
        return;
    }
    if (ffs[i] <= 0) return;

    int lox = (int)floorf(px - KHALF);
    int loy = (int)floorf(py - KHALF);
    int tx0 = max(lox, 0) >> 4, tx1 = min(lox + 3, NBX - 1) >> 4;
    int ty0 = max(loy, 0) >> 3, ty1 = min(loy + 3, NBY - 1) >> 3;
    uint4 entry = make_uint4(__float_as_uint(px), __float_as_uint(py),
                             (((unsigned)ctrl[2 * i]) << 8) | (unsigned)ctrl[2 * i + 1], 0u);
    for (int tx = tx0; tx <= tx1; ++tx) {
        for (int ty = ty0; ty <= ty1; ++ty) {
            int t = tx * TGY + ty;
            int slot = atomicAdd(&ff_counts[t * CSTRIDE], 1);
            if (slot < FCAP) ff_buckets[(size_t)t * FCAP + slot] = entry;
        }
    }
}

// Pass 2: per-tile FF channel accumulation + ff_scale, entirely in LDS.
__global__ void __launch_bounds__(512) ff_tile_kernel(
        const uint4* __restrict__ ff_buckets,
        const int* __restrict__ ff_counts,
        float* __restrict__ ff_scale) {
    __shared__ float acc[FTX * FTY * RS];   // 74240 B
    int t = blockIdx.x;
    int X0 = (t / TGY) * FTX;
    int Y0 = (t % TGY) * FTY;
    int tid = threadIdx.x;

    for (int j = tid; j < FTX * FTY * RS; j += 512) acc[j] = 0.f;
    __syncthreads();

    int n = min(ff_counts[t * CSTRIDE], FCAP);
    for (int e = tid; e < n; e += 512) {
        uint4 entry = ff_buckets[(size_t)t * FCAP + e];   // coalesced
        float px = __uint_as_float(entry.x);
        float py = __uint_as_float(entry.y);
        int ck = (int)(entry.z >> 8);
        int ce = (int)(entry.z & 255u);
        int lox, loy;
        float wx[K], wy[K];
        axis_weights4(px, NBX, lox, wx);
        axis_weights4(py, NBY, loy, wy);
#pragma unroll
        for (int kx = 0; kx < K; ++kx) {
            int gx = lox + kx - X0;
            if (gx < 0 || gx >= FTX || wx[kx] == 0.f) continue;
#pragma unroll
            for (int ky = 0; ky < K; ++ky) {
                int gy = loy + ky - Y0;
                if (gy < 0 || gy >= FTY) continue;
                float w2 = wx[kx] * wy[ky];
                if (w2 != 0.f) {
                    float* row = acc + (gx * FTY + gy) * RS;
                    atomicAdd(&row[ck], w2);        // ds_add_f32
                    atomicAdd(&row[48 + ce], w2);
                }
            }
        }
    }
    __syncthreads();

    // 128 bins x 4 threads: each thread covers 12 ck + 24 ce channels.
    int lb = tid >> 2, q = tid & 3;
    const float* row = acc + lb * RS;
    float raw = 0.f, effck = 0.f, effce = 0.f;
#pragma unroll
    for (int c = 0; c < 12; ++c) {
        float v = row[12 * q + c];
        raw += v;
        effck += ceilf(v * 0.125f);
    }
#pragma unroll
    for (int c = 0; c < 24; ++c) {
        effce += ceilf(row[48 + 24 * q + c] * 0.25f);
    }
    raw   += __shfl_xor(raw, 1);   raw   += __shfl_xor(raw, 2);
    effck += __shfl_xor(effck, 1); effck += __shfl_xor(effck, 2);
    effce += __shfl_xor(effce, 1); effce += __shfl_xor(effce, 2);
    if (q == 0) {
        float eff = fmaxf(effck * 8.f, effce * 4.f);
        int gx = X0 + (lb >> 3);
        int gy = Y0 + (lb & 7);
        ff_scale[gx * NBY + gy] = fmaxf(eff / fmaxf(raw, 1e-6f), 1.f);
    }
}

// Pass 3: per-instance gather.
__global__ void __launch_bounds__(256) area_kernel(
        const float* __restrict__ pos,
        const int* __restrict__ luts,
        const int* __restrict__ ffs,
        const float* __restrict__ lut_dem,
        const float* __restrict__ ff_scale,
        float* __restrict__ out) {
    int i = blockIdx.x * blockDim.x + threadIdx.x;
    if (i >= N_INST) return;
    bool is_lut = luts[i] > 0;
    bool is_ff  = (ffs[i] > 0) && !is_lut;
    if (!is_lut && !is_ff) { out[i] = 0.f; return; }

    float px = pos[2 * i], py = pos[2 * i + 1];
    int lox, loy;
    float wx[K], wy[K];
    axis_weights4(px, NBX, lox, wx);
    axis_weights4(py, NBY, loy, wy);

    const float* tbl = is_lut ? lut_dem : ff_scale;
    float acc = 0.f;
#pragma unroll
    for (int kx = 0; kx < K; ++kx) {
        int gx = min(max(lox + kx, 0), NBX - 1);
#pragma unroll
        for (int ky = 0; ky < K; ++ky) {
            int gy = min(max(loy + ky, 0), NBY - 1);
            float w2 = wx[kx] * wy[ky];
            float v = tbl[gx * NBY + gy];
            float s = is_lut ? fmaxf(v * 0.0625f, 1.f) : v;
            acc += w2 * s;
        }
    }
    out[i] = acc;
}

extern "C" void kernel_launch(void* const* d_in, const int* in_sizes, int n_in,
                              void* d_out, int out_size, void* d_ws, size_t ws_size,
                              hipStream_t stream) {
    const float* pos  = (const float*)d_in[0];
    const int*   luts = (const int*)d_in[1];
    const int*   ffs  = (const int*)d_in[2];
    const int*   ctrl = (const int*)d_in[3];
    float* out = (float*)d_out;

    // ws: ff_counts[NFT*16] | lut_dem[NB] | ff_scale[NB] | ff_buckets[NFT][FCAP] (uint4)
    int*   ff_counts  = (int*)d_ws;
    float* lut_dem    = (float*)(ff_counts + NFT * CSTRIDE);
    float* ff_scale   = lut_dem + NB;
    uint4* ff_buckets = (uint4*)(ff_scale + NB);   // 16B-aligned

    // Zero ff_counts + lut_dem (contiguous ~1.2MB). ff_scale fully written by ff_tile_kernel.
    hipMemsetAsync(d_ws, 0, (size_t)(NFT * CSTRIDE + NB) * sizeof(int), stream);

    dim3 blk(256);
    dim3 grdI((N_INST + 255) / 256);

    classify_kernel<<<grdI, blk, 0, stream>>>(pos, luts, ffs, ctrl,
                                              lut_dem, ff_counts, ff_buckets);
    ff_tile_kernel<<<NFT, dim3(512), 0, stream>>>(ff_buckets, ff_counts, ff_scale);
    area_kernel<<<grdI, blk, 0, stream>>>(pos, luts, ffs, lut_dem, ff_scale, out);
}

// Round 8
// 231.639 us; speedup vs baseline: 2.8096x; 2.8096x over previous
//
#include <hip/hip_runtime.h>

#define N_INST   1000000
#define NBX      512
#define NBY      512
#define NB       (NBX * NBY)
#define NUM_CKSR 48
#define NUM_CE   96
#define K        4          // w[4] of the reference 5-tap is identically 0 (half = 1.5 exactly)

// Unified tiling: 16x8-bin tiles, dilated bucketing (4-bin footprint straddles <= 2x2 tiles).
// Dilation means each tile sees ALL contributions to its interior bins -> per-tile-final
// sums -> no global atomics anywhere.
#define FTX   16
#define FTY   8
#define TGX   (NBX / FTX)   // 32
#define TGY   (NBY / FTY)   // 64
#define NFT   (TGX * TGY)   // 2048
#define FCAP  1024          // mean ~684 entries/tile (570 lut + 114 ff), >12 sigma headroom
#define RS    145           // LDS row: 48 ck + 96 ce + slot144 = lut demand (odd stride)

#define CSTRIDE 16          // one bucket cursor per 64B line (R5: kills line-atomic serialization)

// Constants folded in DOUBLE then rounded once to f32 (matches JAX): half = 1.5f exactly.
#define KHALF  ((float)(2.5 * 0.6))
#define KDENOM ((float)(0.6 * 1.4142135623730951))

// 4-tap truncated-Gaussian weights. Shared erf edges (hi_c[k] == lo_c[k+1] are the same
// fp expression in the reference) -> 5 phis, bit-identical to the reference's 10-phi form;
// w[4] == 0.0 exactly and is dropped. When w[k] != 0, bin lo+k is in [0, nbins).
__device__ __forceinline__ void axis_weights4(float pos, int nbins, int& lo_out, float w[K]) {
    float wlo = pos - KHALF;
    float whi = pos + KHALF;
    int lo_bin = (int)floorf(wlo);
    lo_out = lo_bin;
    float phi[K + 1];
#pragma unroll
    for (int k = 0; k <= K; ++k) {
        float e = (float)(lo_bin + k);
        float ec = fminf(fmaxf(e, wlo), whi);
        phi[k] = 0.5f * (1.f + erff((ec - pos) / KDENOM));
    }
    float wsum = 0.f;
#pragma unroll
    for (int k = 0; k < K; ++k) {
        int b = lo_bin + k;
        float ww = phi[k + 1] - phi[k];
        if (b < 0 || b >= nbins) ww = 0.f;
        w[k] = ww;
        wsum += ww;
    }
    float d = wsum + 1e-12f;
#pragma unroll
    for (int k = 0; k < K; ++k) w[k] = w[k] / d;   // division, as in reference
}

// Pass 1: bucket every active instance into all dilated 16x8 tiles its footprint touches.
// Lut entries fill from slot 0 up; ff entries from slot FCAP-1 down (separate cursors,
// separate cachelines) -> ff_tile processes two wave-coherent ranges.
__global__ void __launch_bounds__(256) classify_kernel(
        const float* __restrict__ pos,
        const int* __restrict__ luts,
        const int* __restrict__ ffs,
        const int* __restrict__ ctrl,
        int* __restrict__ lut_cursors,     // [NFT*CSTRIDE] zeroed
        int* __restrict__ ff_cursors,      // [NFT*CSTRIDE] zeroed
        uint4* __restrict__ buckets) {     // [NFT][FCAP]
    int i = blockIdx.x * blockDim.x + threadIdx.x;
    if (i >= N_INST) return;
    bool is_lut = luts[i] > 0;
    bool is_ff;
    if (is_lut) { is_ff = false; } else { is_ff = ffs[i] > 0; }
    if (!is_lut && !is_ff) return;

    float px = pos[2 * i], py = pos[2 * i + 1];
    unsigned meta = is_lut ? 0x80000000u
                           : ((((unsigned)ctrl[2 * i]) << 8) | (unsigned)ctrl[2 * i + 1]);
    uint4 entry = make_uint4(__float_as_uint(px), __float_as_uint(py), meta, 0u);

    int lox = (int)floorf(px - KHALF);
    int loy = (int)floorf(py - KHALF);
    int tx0 = max(lox, 0) >> 4, tx1 = min(lox + 3, NBX - 1) >> 4;
    int ty0 = max(loy, 0) >> 3, ty1 = min(loy + 3, NBY - 1) >> 3;
    for (int tx = tx0; tx <= tx1; ++tx) {
        for (int ty = ty0; ty <= ty1; ++ty) {
            int t = tx * TGY + ty;
            int slot;
            if (is_lut) {
                slot = atomicAdd(&lut_cursors[t * CSTRIDE], 1);
            } else {
                slot = FCAP - 1 - atomicAdd(&ff_cursors[t * CSTRIDE], 1);
            }
            if (slot >= 0 && slot < FCAP)
                buckets[(size_t)t * FCAP + slot] = entry;
        }
    }
}

// Pass 2: per-tile accumulation of lut demand + ff channels in LDS, then final
// lut_scale / ff_scale for the tile's interior bins via plain stores.
__global__ void __launch_bounds__(512) tile_kernel(
        const uint4* __restrict__ buckets,
        const int* __restrict__ lut_cursors,
        const int* __restrict__ ff_cursors,
        float* __restrict__ lut_scale,
        float* __restrict__ ff_scale) {
    __shared__ float acc[FTX * FTY * RS];   // 74240 B
    int t = blockIdx.x;
    int X0 = (t / TGY) * FTX;
    int Y0 = (t % TGY) * FTY;
    int tid = threadIdx.x;

    for (int j = tid; j < FTX * FTY * RS; j += 512) acc[j] = 0.f;
    __syncthreads();

    int nl = min(lut_cursors[t * CSTRIDE], FCAP);
    int nf = min(ff_cursors[t * CSTRIDE], FCAP);
    int ffstart = FCAP - nf;

    // Lut range [0, nl): one ds_add per in-tile cell into slot 144.
    for (int e = tid; e < nl; e += 512) {
        uint4 entry = buckets[(size_t)t * FCAP + e];
        float px = __uint_as_float(entry.x);
        float py = __uint_as_float(entry.y);
        int lox, loy;
        float wx[K], wy[K];
        axis_weights4(px, NBX, lox, wx);
        axis_weights4(py, NBY, loy, wy);
#pragma unroll
        for (int kx = 0; kx < K; ++kx) {
            int gx = lox + kx - X0;
            if (gx < 0 || gx >= FTX || wx[kx] == 0.f) continue;
#pragma unroll
            for (int ky = 0; ky < K; ++ky) {
                int gy = loy + ky - Y0;
                if (gy < 0 || gy >= FTY) continue;
                float w2 = wx[kx] * wy[ky];
                if (w2 != 0.f)
                    atomicAdd(&acc[(gx * FTY + gy) * RS + 144], w2);
            }
        }
    }

    // FF range [FCAP-nf, FCAP): two ds_adds per in-tile cell.
    for (int e = ffstart + tid; e < FCAP; e += 512) {
        uint4 entry = buckets[(size_t)t * FCAP + e];
        float px = __uint_as_float(entry.x);
        float py = __uint_as_float(entry.y);
        int ck = (int)((entry.z >> 8) & 255u);
        int ce = (int)(entry.z & 255u);
        int lox, loy;
        float wx[K], wy[K];
        axis_weights4(px, NBX, lox, wx);
        axis_weights4(py, NBY, loy, wy);
#pragma unroll
        for (int kx = 0; kx < K; ++kx) {
            int gx = lox + kx - X0;
            if (gx < 0 || gx >= FTX || wx[kx] == 0.f) continue;
#pragma unroll
            for (int ky = 0; ky < K; ++ky) {
                int gy = loy + ky - Y0;
                if (gy < 0 || gy >= FTY) continue;
                float w2 = wx[kx] * wy[ky];
                if (w2 != 0.f) {
                    float* row = acc + (gx * FTY + gy) * RS;
                    atomicAdd(&row[ck], w2);        // ds_add_f32
                    atomicAdd(&row[48 + ce], w2);
                }
            }
        }
    }
    __syncthreads();

    // 128 bins x 4 threads: q0..q3 each cover 12 ck + 24 ce channels; q0 writes ff_scale,
    // q1 writes lut_scale (slot 144 is the complete, final lut demand for this bin).
    int lb = tid >> 2, q = tid & 3;
    const float* row = acc + lb * RS;
    float raw = 0.f, effck = 0.f, effce = 0.f;
#pragma unroll
    for (int c = 0; c < 12; ++c) {
        float v = row[12 * q + c];
        raw += v;
        effck += ceilf(v * 0.125f);
    }
#pragma unroll
    for (int c = 0; c < 24; ++c) {
        effce += ceilf(row[48 + 24 * q + c] * 0.25f);
    }
    raw   += __shfl_xor(raw, 1);   raw   += __shfl_xor(raw, 2);
    effck += __shfl_xor(effck, 1); effck += __shfl_xor(effck, 2);
    effce += __shfl_xor(effce, 1); effce += __shfl_xor(effce, 2);
    int gx = X0 + (lb >> 3);
    int gy = Y0 + (lb & 7);
    if (q == 0) {
        float eff = fmaxf(effck * 8.f, effce * 4.f);
        ff_scale[gx * NBY + gy] = fmaxf(eff / fmaxf(raw, 1e-6f), 1.f);
    } else if (q == 1) {
        lut_scale[gx * NBY + gy] = fmaxf(row[144] * 0.0625f, 1.f);   // /16, exact pow2
    }
}

// Pass 3: per-instance gather.
__global__ void __launch_bounds__(256) area_kernel(
        const float* __restrict__ pos,
        const int* __restrict__ luts,
        const int* __restrict__ ffs,
        const float* __restrict__ lut_scale,
        const float* __restrict__ ff_scale,
        float* __restrict__ out) {
    int i = blockIdx.x * blockDim.x + threadIdx.x;
    if (i >= N_INST) return;
    bool is_lut = luts[i] > 0;
    bool is_ff  = (ffs[i] > 0) && !is_lut;
    if (!is_lut && !is_ff) { out[i] = 0.f; return; }

    float px = pos[2 * i], py = pos[2 * i + 1];
    int lox, loy;
    float wx[K], wy[K];
    axis_weights4(px, NBX, lox, wx);
    axis_weights4(py, NBY, loy, wy);

    const float* tbl = is_lut ? lut_scale : ff_scale;
    float acc = 0.f;
#pragma unroll
    for (int kx = 0; kx < K; ++kx) {
        int gx = min(max(lox + kx, 0), NBX - 1);
#pragma unroll
        for (int ky = 0; ky < K; ++ky) {
            int gy = min(max(loy + ky, 0), NBY - 1);
            acc += wx[kx] * wy[ky] * tbl[gx * NBY + gy];
        }
    }
    out[i] = acc;
}

extern "C" void kernel_launch(void* const* d_in, const int* in_sizes, int n_in,
                              void* d_out, int out_size, void* d_ws, size_t ws_size,
                              hipStream_t stream) {
    const float* pos  = (const float*)d_in[0];
    const int*   luts = (const int*)d_in[1];
    const int*   ffs  = (const int*)d_in[2];
    const int*   ctrl = (const int*)d_in[3];
    float* out = (float*)d_out;

    // ws: lut_cursors[NFT*16] | ff_cursors[NFT*16] | lut_scale[NB] | ff_scale[NB]
    //     | buckets[NFT][FCAP] (uint4, 32MB)
    int*   lut_cursors = (int*)d_ws;
    int*   ff_cursors  = lut_cursors + NFT * CSTRIDE;
    float* lut_scale   = (float*)(ff_cursors + NFT * CSTRIDE);
    float* ff_scale    = lut_scale + NB;
    uint4* buckets     = (uint4*)(ff_scale + NB);   // 16B-aligned

    // Zero only the cursors (256KB); both scale planes are fully written by tile_kernel.
    hipMemsetAsync(d_ws, 0, (size_t)(2 * NFT * CSTRIDE) * sizeof(int), stream);

    dim3 blk(256);
    dim3 grdI((N_INST + 255) / 256);

    classify_kernel<<<grdI, blk, 0, stream>>>(pos, luts, ffs, ctrl,
                                              lut_cursors, ff_cursors, buckets);
    tile_kernel<<<NFT, dim3(512), 0, stream>>>(buckets, lut_cursors, ff_cursors,
                                               lut_scale, ff_scale);
    area_kernel<<<grdI, blk, 0, stream>>>(pos, luts, ffs, lut_scale, ff_scale, out);
}

// Round 10
// 205.582 us; speedup vs baseline: 3.1657x; 1.1267x over previous
//
#include <hip/hip_runtime.h>

#define N_INST   1000000
#define NBX      512
#define NBY      512
#define NB       (NBX * NBY)
#define NUM_CKSR 48
#define NUM_CE   96
#define K        4          // w[4] of the reference 5-tap is identically 0 (half = 1.5 exactly)

// Tiling: 16x8-bin tiles. ff entries are dilated (all tiles the footprint touches), with
// EXACT f32 weights (ceil(c/8) at c->0+ is sharp: quantization is forbidden on the ff path).
// lut entries go to the center tile only (u10 weights: lut path has no ceil, error ~1e-4)
// and accumulate into a dilated 20x12 LDS patch with global-atomic writeback.
#define FTX   16
#define FTY   8
#define TGX   (NBX / FTX)   // 32
#define TGY   (NBY / FTY)   // 64
#define NFT   (TGX * TGY)   // 2048
#define CAPL  512           // lut mean 349/tile, +8 sigma
#define CAPF  256           // ff mean 114/tile (dup 1.633), +13 sigma
#define RS    145           // 48 ck + 96 ce + pad (odd stride, conflict-free)
#define ACCW  (FTX * FTY * RS)      // 18560 words
#define PXW   20            // lut patch: x in [X0-2, X0+17]
#define PYW   12            // y in [Y0-2, Y0+9]
#define LDSW  (ACCW + PXW * PYW)    // 18800 words = 75200 B -> 2 blocks/CU

#define CSTRIDE 16          // one cursor per 64B line (R5 lesson)

// Constants folded in DOUBLE then rounded once to f32 (matches JAX): half = 1.5f exactly.
#define KHALF  ((float)(2.5 * 0.6))
#define KDENOM ((float)(0.6 * 1.4142135623730951))

// 4-tap truncated-Gaussian weights; 5 shared erf edges, bit-identical to reference.
__device__ __forceinline__ void axis_weights4(float pos, int nbins, int& lo_out, float w[K]) {
    float wlo = pos - KHALF;
    float whi = pos + KHALF;
    int lo_bin = (int)floorf(wlo);
    lo_out = lo_bin;
    float phi[K + 1];
#pragma unroll
    for (int k = 0; k <= K; ++k) {
        float e = (float)(lo_bin + k);
        float ec = fminf(fmaxf(e, wlo), whi);
        phi[k] = 0.5f * (1.f + erff((ec - pos) / KDENOM));
    }
    float wsum = 0.f;
#pragma unroll
    for (int k = 0; k < K; ++k) {
        int b = lo_bin + k;
        float ww = phi[k + 1] - phi[k];
        if (b < 0 || b >= nbins) ww = 0.f;
        w[k] = ww;
        wsum += ww;
    }
    float d = wsum + 1e-12f;
#pragma unroll
    for (int k = 0; k < K; ++k) w[k] = w[k] / d;   // division, as in reference
}

// Pass 1: weights computed ONCE per instance. lut -> u10-packed 16B entry, center tile.
// ff -> exact-f32 SoA entries (wx4, wy4, meta), dilated tiles.
__global__ void __launch_bounds__(256) classify_kernel(
        const float* __restrict__ pos,
        const int* __restrict__ luts,
        const int* __restrict__ ffs,
        const int* __restrict__ ctrl,
        int* __restrict__ lut_cur,        // [NFT*CSTRIDE] zeroed
        int* __restrict__ ff_cur,         // [NFT*CSTRIDE] zeroed
        uint4* __restrict__ lutb,         // [NFT][CAPL]
        float4* __restrict__ ffwx,        // [NFT*CAPF]
        float4* __restrict__ ffwy,        // [NFT*CAPF]
        unsigned* __restrict__ ffmeta) {  // [NFT*CAPF]
    int i = blockIdx.x * blockDim.x + threadIdx.x;
    if (i >= N_INST) return;
    bool is_lut = luts[i] > 0;
    bool is_ff  = !is_lut && (ffs[i] > 0);
    if (!is_lut && !is_ff) return;

    float px = pos[2 * i], py = pos[2 * i + 1];
    int lox, loy;
    float wx[K], wy[K];
    axis_weights4(px, NBX, lox, wx);
    axis_weights4(py, NBY, loy, wy);

    if (is_lut) {
        int tx = ((int)px) >> 4, ty = ((int)py) >> 3;
        int t = tx * TGY + ty;
        unsigned q[8];
#pragma unroll
        for (int k = 0; k < K; ++k) {
            q[k]     = min(1023u, (unsigned)rintf(wx[k] * 1024.f));
            q[4 + k] = min(1023u, (unsigned)rintf(wy[k] * 1024.f));
        }
        unsigned rx = (unsigned)(lox - tx * FTX + 2);   // [0,16]
        unsigned ry = (unsigned)(loy - ty * FTY + 2);   // [0,8]
        uint4 e;
        e.x = q[0] | (q[1] << 10) | (q[2] << 20);
        e.y = q[3] | (q[4] << 10) | (q[5] << 20);
        e.z = q[6] | (q[7] << 10) | (rx << 20) | (ry << 25);
        e.w = 0u;
        int slot = atomicAdd(&lut_cur[t * CSTRIDE], 1);
        if (slot < CAPL) lutb[(size_t)t * CAPL + slot] = e;
        return;
    }

    float4 w1 = make_float4(wx[0], wx[1], wx[2], wx[3]);
    float4 w2 = make_float4(wy[0], wy[1], wy[2], wy[3]);
    unsigned ck   = (unsigned)ctrl[2 * i];
    unsigned ce48 = 48u + (unsigned)ctrl[2 * i + 1];

    int tx0 = max(lox, 0) >> 4, tx1 = min(lox + 3, NBX - 1) >> 4;
    int ty0 = max(loy, 0) >> 3, ty1 = min(loy + 3, NBY - 1) >> 3;
    for (int tx = tx0; tx <= tx1; ++tx) {
        for (int ty = ty0; ty <= ty1; ++ty) {
            int t = tx * TGY + ty;
            unsigned cx = (unsigned)(lox - tx * FTX + 4);   // [1,19]
            unsigned cy = (unsigned)(loy - ty * FTY + 4);   // [1,11]
            int slot = atomicAdd(&ff_cur[t * CSTRIDE], 1);
            if (slot < CAPF) {
                size_t idx = (size_t)t * CAPF + slot;
                ffwx[idx] = w1;
                ffwy[idx] = w2;
                ffmeta[idx] = cx | (cy << 8) | (ck << 16) | (ce48 << 24);
            }
        }
    }
}

// Pass 2: erf-free tile accumulation. lut -> LDS patch -> global atomic writeback;
// ff -> interior channel rows (exact f32 products, bit-matching reference) -> ff_scale.
__global__ void __launch_bounds__(1024) tile_kernel(
        const uint4* __restrict__ lutb,
        const float4* __restrict__ ffwx,
        const float4* __restrict__ ffwy,
        const unsigned* __restrict__ ffmeta,
        const int* __restrict__ lut_cur,
        const int* __restrict__ ff_cur,
        float* __restrict__ lut_dem,
        float* __restrict__ ff_scale) {
    __shared__ float lds[LDSW];
    int t = blockIdx.x;
    int X0 = (t / TGY) * FTX;
    int Y0 = (t % TGY) * FTY;
    int tid = threadIdx.x;

    for (int j = tid; j < LDSW; j += 1024) lds[j] = 0.f;
    __syncthreads();

    // LUT entries: decode u10 weights, 16 unconditional patch ds_adds.
    int nl = min(lut_cur[t * CSTRIDE], CAPL);
    for (int e = tid; e < nl; e += 1024) {
        uint4 a = lutb[(size_t)t * CAPL + e];
        const float s = 1.f / 1024.f;
        float fx[4] = { (float)(a.x & 1023u) * s, (float)((a.x >> 10) & 1023u) * s,
                        (float)((a.x >> 20) & 1023u) * s, (float)(a.y & 1023u) * s };
        float fy[4] = { (float)((a.y >> 10) & 1023u) * s, (float)((a.y >> 20) & 1023u) * s,
                        (float)(a.z & 1023u) * s, (float)((a.z >> 10) & 1023u) * s };
        unsigned rx = (a.z >> 20) & 31u, ry = (a.z >> 25) & 15u;
        int base = ACCW + (int)rx * PYW + (int)ry;
#pragma unroll
        for (int kx = 0; kx < K; ++kx) {
            float wv = fx[kx];
            int rb = base + kx * PYW;
#pragma unroll
            for (int ky = 0; ky < K; ++ky)
                atomicAdd(&lds[rb + ky], wv * fy[ky]);
        }
    }

    // FF entries: exact f32 weights, predicated interior ds_adds.
    int nf = min(ff_cur[t * CSTRIDE], CAPF);
    for (int e = tid; e < nf; e += 1024) {
        size_t idx = (size_t)t * CAPF + e;
        float4 a = ffwx[idx];
        float4 b = ffwy[idx];
        unsigned m = ffmeta[idx];
        float fx[4] = { a.x, a.y, a.z, a.w };
        float fy[4] = { b.x, b.y, b.z, b.w };
        int cx = (int)(m & 255u) - 4;          // lox - X0
        int cy = (int)((m >> 8) & 255u) - 4;   // loy - Y0
        int ck   = (int)((m >> 16) & 255u);
        int ce48 = (int)(m >> 24);
#pragma unroll
        for (int kx = 0; kx < K; ++kx) {
            int gx = cx + kx;
            if ((unsigned)gx >= FTX) continue;
            float wv = fx[kx];
#pragma unroll
            for (int ky = 0; ky < K; ++ky) {
                int gy = cy + ky;
                if ((unsigned)gy >= FTY) continue;
                float w2 = wv * fy[ky];
                if (w2 != 0.f) {
                    float* row = lds + (gx * FTY + gy) * RS;
                    atomicAdd(row + ck, w2);
                    atomicAdd(row + ce48, w2);
                }
            }
        }
    }
    __syncthreads();

    if (tid < 512) {
        // ff_scale: 128 bins x 4 threads.
        int lb = tid >> 2, q = tid & 3;
        const float* row = lds + lb * RS;
        float raw = 0.f, effck = 0.f, effce = 0.f;
#pragma unroll
        for (int c = 0; c < 12; ++c) {
            float v = row[12 * q + c];
            raw += v;
            effck += ceilf(v * 0.125f);
        }
#pragma unroll
        for (int c = 0; c < 24; ++c) {
            effce += ceilf(row[48 + 24 * q + c] * 0.25f);
        }
        raw   += __shfl_xor(raw, 1);   raw   += __shfl_xor(raw, 2);
        effck += __shfl_xor(effck, 1); effck += __shfl_xor(effck, 2);
        effce += __shfl_xor(effce, 1); effce += __shfl_xor(effce, 2);
        if (q == 0) {
            float eff = fmaxf(effck * 8.f, effce * 4.f);
            int gx = X0 + (lb >> 3);
            int gy = Y0 + (lb & 7);
            ff_scale[gx * NBY + gy] = fmaxf(eff / fmaxf(raw, 1e-6f), 1.f);
        }
    } else if (tid < 512 + PXW * PYW) {
        // lut patch writeback.
        int j = tid - 512;
        float v = lds[ACCW + j];
        if (v != 0.f) {
            int gx = X0 - 2 + j / PYW;
            int gy = Y0 - 2 + j % PYW;
            if (gx >= 0 && gx < NBX && gy >= 0 && gy < NBY)
                unsafeAtomicAdd(&lut_dem[gx * NBY + gy], v);
        }
    }
}

// Pass 3: per-instance gather (exact f32 weights).
__global__ void __launch_bounds__(256) area_kernel(
        const float* __restrict__ pos,
        const int* __restrict__ luts,
        const int* __restrict__ ffs,
        const float* __restrict__ lut_dem,
        const float* __restrict__ ff_scale,
        float* __restrict__ out) {
    int i = blockIdx.x * blockDim.x + threadIdx.x;
    if (i >= N_INST) return;
    bool is_lut = luts[i] > 0;
    bool is_ff  = (ffs[i] > 0) && !is_lut;
    if (!is_lut && !is_ff) { out[i] = 0.f; return; }

    float px = pos[2 * i], py = pos[2 * i + 1];
    int lox, loy;
    float wx[K], wy[K];
    axis_weights4(px, NBX, lox, wx);
    axis_weights4(py, NBY, loy, wy);

    const float* tbl = is_lut ? lut_dem : ff_scale;
    float acc = 0.f;
#pragma unroll
    for (int kx = 0; kx < K; ++kx) {
        int gx = min(max(lox + kx, 0), NBX - 1);
#pragma unroll
        for (int ky = 0; ky < K; ++ky) {
            int gy = min(max(loy + ky, 0), NBY - 1);
            float w2 = wx[kx] * wy[ky];
            float v = tbl[gx * NBY + gy];
            float sc = is_lut ? fmaxf(v * 0.0625f, 1.f) : v;
            acc += w2 * sc;
        }
    }
    out[i] = acc;
}

extern "C" void kernel_launch(void* const* d_in, const int* in_sizes, int n_in,
                              void* d_out, int out_size, void* d_ws, size_t ws_size,
                              hipStream_t stream) {
    const float* pos  = (const float*)d_in[0];
    const int*   luts = (const int*)d_in[1];
    const int*   ffs  = (const int*)d_in[2];
    const int*   ctrl = (const int*)d_in[3];
    float* out = (float*)d_out;

    // ws: lut_cur[NFT*16] | ff_cur[NFT*16] | lut_dem[NB] | ff_scale[NB]
    //     | lutb[NFT*CAPL] uint4 (16MB) | ffwx[NFT*CAPF] float4 (8MB)
    //     | ffwy[NFT*CAPF] float4 (8MB) | ffmeta[NFT*CAPF] u32 (2MB)
    int*      lut_cur  = (int*)d_ws;
    int*      ff_cur   = lut_cur + NFT * CSTRIDE;
    float*    lut_dem  = (float*)(ff_cur + NFT * CSTRIDE);
    float*    ff_scale = lut_dem + NB;
    uint4*    lutb     = (uint4*)(ff_scale + NB);        // byte offset 2359296, 16B-aligned
    float4*   ffwx     = (float4*)(lutb + (size_t)NFT * CAPL);
    float4*   ffwy     = ffwx + (size_t)NFT * CAPF;
    unsigned* ffmeta   = (unsigned*)(ffwy + (size_t)NFT * CAPF);

    // Zero cursors + lut_dem (contiguous). ff_scale fully written by tile_kernel.
    hipMemsetAsync(d_ws, 0, (size_t)(2 * NFT * CSTRIDE + NB) * sizeof(int), stream);

    dim3 blk(256);
    dim3 grdI((N_INST + 255) / 256);

    classify_kernel<<<grdI, blk, 0, stream>>>(pos, luts, ffs, ctrl,
                                              lut_cur, ff_cur, lutb, ffwx, ffwy, ffmeta);
    tile_kernel<<<NFT, dim3(1024), 0, stream>>>(lutb, ffwx, ffwy, ffmeta,
                                                lut_cur, ff_cur, lut_dem, ff_scale);
    area_kernel<<<grdI, blk, 0, stream>>>(pos, luts, ffs, lut_dem, ff_scale, out);
}

// Round 11
// 140.442 us; speedup vs baseline: 4.6340x; 1.4638x over previous
//
#include <hip/hip_runtime.h>

#define N_INST   1000000
#define NBX      512
#define NBY      512
#define NB       (NBX * NBY)
#define NUM_CKSR 48
#define NUM_CE   96
#define K        4          // w[4] of the reference 5-tap is identically 0 (half = 1.5 exactly)

// Tiling: 16x8-bin tiles. ff entries dilated with EXACT f32 weights (ceil(c/8) at c->0+ is
// sharp; R9 proved quantization fails). lut entries u10-quantized to the center tile and
// accumulated in an INTEGER LDS patch (ds_add_u32 native -- no fp-CAS loop), then written
// back with global fp atomics. ff rows use unsafeAtomicAdd -> ds_add_f32.
#define FTX   16
#define FTY   8
#define TGX   (NBX / FTX)   // 32
#define TGY   (NBY / FTY)   // 64
#define NFT   (TGX * TGY)   // 2048
#define CAPL  512           // lut mean 349/tile, +8 sigma
#define CAPF  256           // ff mean 114/tile (dup 1.633), +13 sigma
#define RS    145           // 48 ck + 96 ce + pad (odd stride, conflict-free)
#define ACCW  (FTX * FTY * RS)      // 18560 words
#define PXW   20            // lut patch: x in [X0-2, X0+17]
#define PYW   12            // y in [Y0-2, Y0+9]

#define CSTRIDE 16          // one cursor per 64B line (R5 lesson)

// Constants folded in DOUBLE then rounded once to f32 (matches JAX): half = 1.5f exactly.
#define KHALF  ((float)(2.5 * 0.6))
#define KDENOM ((float)(0.6 * 1.4142135623730951))

// 4-tap truncated-Gaussian weights; 5 shared erf edges, bit-identical to reference.
__device__ __forceinline__ void axis_weights4(float pos, int nbins, int& lo_out, float w[K]) {
    float wlo = pos - KHALF;
    float whi = pos + KHALF;
    int lo_bin = (int)floorf(wlo);
    lo_out = lo_bin;
    float phi[K + 1];
#pragma unroll
    for (int k = 0; k <= K; ++k) {
        float e = (float)(lo_bin + k);
        float ec = fminf(fmaxf(e, wlo), whi);
        phi[k] = 0.5f * (1.f + erff((ec - pos) / KDENOM));
    }
    float wsum = 0.f;
#pragma unroll
    for (int k = 0; k < K; ++k) {
        int b = lo_bin + k;
        float ww = phi[k + 1] - phi[k];
        if (b < 0 || b >= nbins) ww = 0.f;
        w[k] = ww;
        wsum += ww;
    }
    float d = wsum + 1e-12f;
#pragma unroll
    for (int k = 0; k < K; ++k) w[k] = w[k] / d;   // division, as in reference
}

// Pass 1: weights computed ONCE per instance. lut -> u10-packed 16B entry, center tile.
// ff -> exact-f32 SoA entries (wx4, wy4, meta), dilated tiles.
__global__ void __launch_bounds__(256) classify_kernel(
        const float* __restrict__ pos,
        const int* __restrict__ luts,
        const int* __restrict__ ffs,
        const int* __restrict__ ctrl,
        int* __restrict__ lut_cur,        // [NFT*CSTRIDE] zeroed
        int* __restrict__ ff_cur,         // [NFT*CSTRIDE] zeroed
        uint4* __restrict__ lutb,         // [NFT][CAPL]
        float4* __restrict__ ffwx,        // [NFT*CAPF]
        float4* __restrict__ ffwy,        // [NFT*CAPF]
        unsigned* __restrict__ ffmeta) {  // [NFT*CAPF]
    int i = blockIdx.x * blockDim.x + threadIdx.x;
    if (i >= N_INST) return;
    bool is_lut = luts[i] > 0;
    bool is_ff  = !is_lut && (ffs[i] > 0);
    if (!is_lut && !is_ff) return;

    float px = pos[2 * i], py = pos[2 * i + 1];
    int lox, loy;
    float wx[K], wy[K];
    axis_weights4(px, NBX, lox, wx);
    axis_weights4(py, NBY, loy, wy);

    if (is_lut) {
        int tx = ((int)px) >> 4, ty = ((int)py) >> 3;
        int t = tx * TGY + ty;
        unsigned q[8];
#pragma unroll
        for (int k = 0; k < K; ++k) {
            q[k]     = min(1023u, (unsigned)rintf(wx[k] * 1024.f));
            q[4 + k] = min(1023u, (unsigned)rintf(wy[k] * 1024.f));
        }
        unsigned rx = (unsigned)(lox - tx * FTX + 2);   // [0,16]
        unsigned ry = (unsigned)(loy - ty * FTY + 2);   // [0,8]
        uint4 e;
        e.x = q[0] | (q[1] << 10) | (q[2] << 20);
        e.y = q[3] | (q[4] << 10) | (q[5] << 20);
        e.z = q[6] | (q[7] << 10) | (rx << 20) | (ry << 25);
        e.w = 0u;
        int slot = atomicAdd(&lut_cur[t * CSTRIDE], 1);
        if (slot < CAPL) lutb[(size_t)t * CAPL + slot] = e;
        return;
    }

    float4 w1 = make_float4(wx[0], wx[1], wx[2], wx[3]);
    float4 w2 = make_float4(wy[0], wy[1], wy[2], wy[3]);
    unsigned ck   = (unsigned)ctrl[2 * i];
    unsigned ce48 = 48u + (unsigned)ctrl[2 * i + 1];

    int tx0 = max(lox, 0) >> 4, tx1 = min(lox + 3, NBX - 1) >> 4;
    int ty0 = max(loy, 0) >> 3, ty1 = min(loy + 3, NBY - 1) >> 3;
    for (int tx = tx0; tx <= tx1; ++tx) {
        for (int ty = ty0; ty <= ty1; ++ty) {
            int t = tx * TGY + ty;
            unsigned cx = (unsigned)(lox - tx * FTX + 4);   // [1,19]
            unsigned cy = (unsigned)(loy - ty * FTY + 4);   // [1,11]
            int slot = atomicAdd(&ff_cur[t * CSTRIDE], 1);
            if (slot < CAPF) {
                size_t idx = (size_t)t * CAPF + slot;
                ffwx[idx] = w1;
                ffwy[idx] = w2;
                ffmeta[idx] = cx | (cy << 8) | (ck << 16) | (ce48 << 24);
            }
        }
    }
}

// Pass 2: erf-free tile accumulation with native LDS atomics only.
__global__ void __launch_bounds__(1024) tile_kernel(
        const uint4* __restrict__ lutb,
        const float4* __restrict__ ffwx,
        const float4* __restrict__ ffwy,
        const unsigned* __restrict__ ffmeta,
        const int* __restrict__ lut_cur,
        const int* __restrict__ ff_cur,
        float* __restrict__ lut_dem,
        float* __restrict__ ff_scale) {
    __shared__ float acc[ACCW];            // ff channel rows
    __shared__ unsigned patch[PXW * PYW];  // lut demand, fixed-point 2^16 (ds_add_u32)
    int t = blockIdx.x;
    int X0 = (t / TGY) * FTX;
    int Y0 = (t % TGY) * FTY;
    int tid = threadIdx.x;

    for (int j = tid; j < ACCW; j += 1024) acc[j] = 0.f;
    if (tid < PXW * PYW) patch[tid] = 0u;
    __syncthreads();

    // LUT entries: decode u10 weights, 16 unconditional integer patch adds.
    int nl = min(lut_cur[t * CSTRIDE], CAPL);
    for (int e = tid; e < nl; e += 1024) {
        uint4 a = lutb[(size_t)t * CAPL + e];
        const float s = 1.f / 1024.f;
        float fx[4] = { (float)(a.x & 1023u) * s, (float)((a.x >> 10) & 1023u) * s,
                        (float)((a.x >> 20) & 1023u) * s, (float)(a.y & 1023u) * s };
        float fy[4] = { (float)((a.y >> 10) & 1023u) * s, (float)((a.y >> 20) & 1023u) * s,
                        (float)(a.z & 1023u) * s, (float)((a.z >> 10) & 1023u) * s };
        unsigned rx = (a.z >> 20) & 31u, ry = (a.z >> 25) & 15u;
        int base = (int)rx * PYW + (int)ry;
#pragma unroll
        for (int kx = 0; kx < K; ++kx) {
            float wv = fx[kx] * 65536.f;
            int rb = base + kx * PYW;
#pragma unroll
            for (int ky = 0; ky < K; ++ky)
                atomicAdd(&patch[rb + ky], (unsigned)rintf(wv * fy[ky]));   // ds_add_u32
        }
    }

    // FF entries: exact f32 weights, predicated interior ds_add_f32 (unsafeAtomicAdd).
    int nf = min(ff_cur[t * CSTRIDE], CAPF);
    for (int e = tid; e < nf; e += 1024) {
        size_t idx = (size_t)t * CAPF + e;
        float4 a = ffwx[idx];
        float4 b = ffwy[idx];
        unsigned m = ffmeta[idx];
        float fx[4] = { a.x, a.y, a.z, a.w };
        float fy[4] = { b.x, b.y, b.z, b.w };
        int cx = (int)(m & 255u) - 4;          // lox - X0
        int cy = (int)((m >> 8) & 255u) - 4;   // loy - Y0
        int ck   = (int)((m >> 16) & 255u);
        int ce48 = (int)(m >> 24);
#pragma unroll
        for (int kx = 0; kx < K; ++kx) {
            int gx = cx + kx;
            if ((unsigned)gx >= FTX) continue;
            float wv = fx[kx];
#pragma unroll
            for (int ky = 0; ky < K; ++ky) {
                int gy = cy + ky;
                if ((unsigned)gy >= FTY) continue;
                float w2 = wv * fy[ky];
                if (w2 != 0.f) {
                    float* row = acc + (gx * FTY + gy) * RS;
                    unsafeAtomicAdd(row + ck, w2);     // ds_add_f32, no CAS loop
                    unsafeAtomicAdd(row + ce48, w2);
                }
            }
        }
    }
    __syncthreads();

    if (tid < 512) {
        // ff_scale: 128 bins x 4 threads.
        int lb = tid >> 2, q = tid & 3;
        const float* row = acc + lb * RS;
        float raw = 0.f, effck = 0.f, effce = 0.f;
#pragma unroll
        for (int c = 0; c < 12; ++c) {
            float v = row[12 * q + c];
            raw += v;
            effck += ceilf(v * 0.125f);
        }
#pragma unroll
        for (int c = 0; c < 24; ++c) {
            effce += ceilf(row[48 + 24 * q + c] * 0.25f);
        }
        raw   += __shfl_xor(raw, 1);   raw   += __shfl_xor(raw, 2);
        effck += __shfl_xor(effck, 1); effck += __shfl_xor(effck, 2);
        effce += __shfl_xor(effce, 1); effce += __shfl_xor(effce, 2);
        if (q == 0) {
            float eff = fmaxf(effck * 8.f, effce * 4.f);
            int gx = X0 + (lb >> 3);
            int gy = Y0 + (lb & 7);
            ff_scale[gx * NBY + gy] = fmaxf(eff / fmaxf(raw, 1e-6f), 1.f);
        }
    } else if (tid < 512 + PXW * PYW) {
        // lut patch writeback (fixed-point -> f32).
        int j = tid - 512;
        unsigned v = patch[j];
        if (v != 0u) {
            int gx = X0 - 2 + j / PYW;
            int gy = Y0 - 2 + j % PYW;
            if (gx >= 0 && gx < NBX && gy >= 0 && gy < NBY)
                unsafeAtomicAdd(&lut_dem[gx * NBY + gy], (float)v * (1.f / 65536.f));
        }
    }
}

// Pass 3: per-instance gather (exact f32 weights).
__global__ void __launch_bounds__(256) area_kernel(
        const float* __restrict__ pos,
        const int* __restrict__ luts,
        const int* __restrict__ ffs,
        const float* __restrict__ lut_dem,
        const float* __restrict__ ff_scale,
        float* __restrict__ out) {
    int i = blockIdx.x * blockDim.x + threadIdx.x;
    if (i >= N_INST) return;
    bool is_lut = luts[i] > 0;
    bool is_ff  = (ffs[i] > 0) && !is_lut;
    if (!is_lut && !is_ff) { out[i] = 0.f; return; }

    float px = pos[2 * i], py = pos[2 * i + 1];
    int lox, loy;
    float wx[K], wy[K];
    axis_weights4(px, NBX, lox, wx);
    axis_weights4(py, NBY, loy, wy);

    const float* tbl = is_lut ? lut_dem : ff_scale;
    float acc = 0.f;
#pragma unroll
    for (int kx = 0; kx < K; ++kx) {
        int gx = min(max(lox + kx, 0), NBX - 1);
#pragma unroll
        for (int ky = 0; ky < K; ++ky) {
            int gy = min(max(loy + ky, 0), NBY - 1);
            float w2 = wx[kx] * wy[ky];
            float v = tbl[gx * NBY + gy];
            float sc = is_lut ? fmaxf(v * 0.0625f, 1.f) : v;
            acc += w2 * sc;
        }
    }
    out[i] = acc;
}

extern "C" void kernel_launch(void* const* d_in, const int* in_sizes, int n_in,
                              void* d_out, int out_size, void* d_ws, size_t ws_size,
                              hipStream_t stream) {
    const float* pos  = (const float*)d_in[0];
    const int*   luts = (const int*)d_in[1];
    const int*   ffs  = (const int*)d_in[2];
    const int*   ctrl = (const int*)d_in[3];
    float* out = (float*)d_out;

    // ws: lut_cur[NFT*16] | ff_cur[NFT*16] | lut_dem[NB] | ff_scale[NB]
    //     | lutb[NFT*CAPL] uint4 (16MB) | ffwx[NFT*CAPF] float4 (8MB)
    //     | ffwy[NFT*CAPF] float4 (8MB) | ffmeta[NFT*CAPF] u32 (2MB)
    int*      lut_cur  = (int*)d_ws;
    int*      ff_cur   = lut_cur + NFT * CSTRIDE;
    float*    lut_dem  = (float*)(ff_cur + NFT * CSTRIDE);
    float*    ff_scale = lut_dem + NB;
    uint4*    lutb     = (uint4*)(ff_scale + NB);
    float4*   ffwx     = (float4*)(lutb + (size_t)NFT * CAPL);
    float4*   ffwy     = ffwx + (size_t)NFT * CAPF;
    unsigned* ffmeta   = (unsigned*)(ffwy + (size_t)NFT * CAPF);

    // Zero cursors + lut_dem (contiguous). ff_scale fully written by tile_kernel.
    hipMemsetAsync(d_ws, 0, (size_t)(2 * NFT * CSTRIDE + NB) * sizeof(int), stream);

    dim3 blk(256);
    dim3 grdI((N_INST + 255) / 256);

    classify_kernel<<<grdI, blk, 0, stream>>>(pos, luts, ffs, ctrl,
                                              lut_cur, ff_cur, lutb, ffwx, ffwy, ffmeta);
    tile_kernel<<<NFT, dim3(1024), 0, stream>>>(lutb, ffwx, ffwy, ffmeta,
                                                lut_cur, ff_cur, lut_dem, ff_scale);
    area_kernel<<<grdI, blk, 0, stream>>>(pos, luts, ffs, lut_dem, ff_scale, out);
}

// Round 12
// 135.381 us; speedup vs baseline: 4.8073x; 1.0374x over previous
//
#include <hip/hip_runtime.h>

#define N_INST   1000000
#define NBX      512
#define NBY      512
#define NB       (NBX * NBY)
#define NUM_CKSR 48
#define NUM_CE   96
#define K        4          // w[4] of the reference 5-tap is identically 0 (half = 1.5 exactly)

// Tiling: 16x8-bin tiles. Entries carry RAW (px,py) — weights are recomputed exactly
// where consumed (tile threads are ~1 entry each; erf chain hides under parallelism).
// ff path needs exact f32 weights (ceil(c/8) sharp at 0+, R9); lut path accumulates
// exact w2 quantized at 2^-16 per add (no ceil on lut -> harmless, R9/R11).
#define FTX   16
#define FTY   8
#define TGX   (NBX / FTX)   // 32
#define TGY   (NBY / FTY)   // 64
#define NFT   (TGX * TGY)   // 2048
#define CAPL  512           // lut mean 349/tile, +8 sigma
#define CAPF  256           // ff mean 114/tile (dup 1.633), +13 sigma
#define RS    145           // 48 ck + 96 ce + pad (odd stride, conflict-free)
#define ACCW  (FTX * FTY * RS)      // 18560 words
#define PXW   20            // lut patch: x in [X0-2, X0+17]
#define PYW   12            // y in [Y0-2, Y0+9]

#define CSTRIDE 16          // one cursor per 64B line (R5 lesson)

// Constants folded in DOUBLE then rounded once to f32 (matches JAX): half = 1.5f exactly.
#define KHALF  ((float)(2.5 * 0.6))
#define KDENOM ((float)(0.6 * 1.4142135623730951))

// 4-tap truncated-Gaussian weights; 5 shared erf edges, bit-identical to reference.
__device__ __forceinline__ void axis_weights4(float pos, int nbins, int& lo_out, float w[K]) {
    float wlo = pos - KHALF;
    float whi = pos + KHALF;
    int lo_bin = (int)floorf(wlo);
    lo_out = lo_bin;
    float phi[K + 1];
#pragma unroll
    for (int k = 0; k <= K; ++k) {
        float e = (float)(lo_bin + k);
        float ec = fminf(fmaxf(e, wlo), whi);
        phi[k] = 0.5f * (1.f + erff((ec - pos) / KDENOM));
    }
    float wsum = 0.f;
#pragma unroll
    for (int k = 0; k < K; ++k) {
        int b = lo_bin + k;
        float ww = phi[k + 1] - phi[k];
        if (b < 0 || b >= nbins) ww = 0.f;
        w[k] = ww;
        wsum += ww;
    }
    float d = wsum + 1e-12f;
#pragma unroll
    for (int k = 0; k < K; ++k) w[k] = w[k] / d;   // division, as in reference
}

// Pass 1: NO erf. lut -> float2(px,py) to center tile; ff -> 16B (px,py,meta) to
// all dilated tiles (floorf-only tile math).
__global__ void __launch_bounds__(256) classify_kernel(
        const float* __restrict__ pos,
        const int* __restrict__ luts,
        const int* __restrict__ ffs,
        const int* __restrict__ ctrl,
        int* __restrict__ lut_cur,        // [NFT*CSTRIDE] zeroed
        int* __restrict__ ff_cur,         // [NFT*CSTRIDE] zeroed
        float2* __restrict__ lutb,        // [NFT][CAPL]
        uint4* __restrict__ ffb) {        // [NFT][CAPF]
    int i = blockIdx.x * blockDim.x + threadIdx.x;
    if (i >= N_INST) return;
    bool is_lut = luts[i] > 0;
    bool is_ff  = !is_lut && (ffs[i] > 0);
    if (!is_lut && !is_ff) return;

    float px = pos[2 * i], py = pos[2 * i + 1];

    if (is_lut) {
        int t = (((int)px) >> 4) * TGY + (((int)py) >> 3);
        int slot = atomicAdd(&lut_cur[t * CSTRIDE], 1);
        if (slot < CAPL) lutb[(size_t)t * CAPL + slot] = make_float2(px, py);
        return;
    }

    unsigned meta = (unsigned)ctrl[2 * i] | (((unsigned)ctrl[2 * i + 1] + 48u) << 8);
    uint4 entry = make_uint4(__float_as_uint(px), __float_as_uint(py), meta, 0u);
    int lox = (int)floorf(px - KHALF);
    int loy = (int)floorf(py - KHALF);
    int tx0 = max(lox, 0) >> 4, tx1 = min(lox + 3, NBX - 1) >> 4;
    int ty0 = max(loy, 0) >> 3, ty1 = min(loy + 3, NBY - 1) >> 3;
    for (int tx = tx0; tx <= tx1; ++tx) {
        for (int ty = ty0; ty <= ty1; ++ty) {
            int t = tx * TGY + ty;
            int slot = atomicAdd(&ff_cur[t * CSTRIDE], 1);
            if (slot < CAPF) ffb[(size_t)t * CAPF + slot] = entry;
        }
    }
}

// Pass 2: weights recomputed here (<=1 lut + <=1 ff entry per thread). Native LDS
// atomics only: u32 patch adds for lut, ds_add_f32 for ff channel rows.
__global__ void __launch_bounds__(1024) tile_kernel(
        const float2* __restrict__ lutb,
        const uint4* __restrict__ ffb,
        const int* __restrict__ lut_cur,
        const int* __restrict__ ff_cur,
        float* __restrict__ lut_dem,
        float* __restrict__ ff_scale) {
    __shared__ float acc[ACCW];            // ff channel rows
    __shared__ unsigned patch[PXW * PYW];  // lut demand, fixed-point 2^16 (ds_add_u32)
    int t = blockIdx.x;
    int X0 = (t / TGY) * FTX;
    int Y0 = (t % TGY) * FTY;
    int tid = threadIdx.x;

    for (int j = tid; j < ACCW; j += 1024) acc[j] = 0.f;
    if (tid < PXW * PYW) patch[tid] = 0u;
    __syncthreads();

    // LUT entries: recompute exact weights, 16 unconditional integer patch adds.
    int nl = min(lut_cur[t * CSTRIDE], CAPL);
    for (int e = tid; e < nl; e += 1024) {
        float2 p = lutb[(size_t)t * CAPL + e];
        int lox, loy;
        float wx[K], wy[K];
        axis_weights4(p.x, NBX, lox, wx);
        axis_weights4(p.y, NBY, loy, wy);
        int base = (lox - (X0 - 2)) * PYW + (loy - (Y0 - 2));   // rx in [0,16], ry in [0,8]
#pragma unroll
        for (int kx = 0; kx < K; ++kx) {
            float wv = wx[kx] * 65536.f;
            int rb = base + kx * PYW;
#pragma unroll
            for (int ky = 0; ky < K; ++ky)
                atomicAdd(&patch[rb + ky], (unsigned)rintf(wv * wy[ky]));   // ds_add_u32
        }
    }

    // FF entries: recompute exact f32 weights, predicated interior ds_add_f32.
    int nf = min(ff_cur[t * CSTRIDE], CAPF);
    for (int e = tid; e < nf; e += 1024) {
        uint4 a = ffb[(size_t)t * CAPF + e];
        float px = __uint_as_float(a.x);
        float py = __uint_as_float(a.y);
        int ck   = (int)(a.z & 255u);
        int ce48 = (int)((a.z >> 8) & 255u);
        int lox, loy;
        float wx[K], wy[K];
        axis_weights4(px, NBX, lox, wx);
        axis_weights4(py, NBY, loy, wy);
        int cx = lox - X0, cy = loy - Y0;
#pragma unroll
        for (int kx = 0; kx < K; ++kx) {
            int gx = cx + kx;
            if ((unsigned)gx >= FTX) continue;
            float wv = wx[kx];
#pragma unroll
            for (int ky = 0; ky < K; ++ky) {
                int gy = cy + ky;
                if ((unsigned)gy >= FTY) continue;
                float w2 = wv * wy[ky];
                if (w2 != 0.f) {
                    float* row = acc + (gx * FTY + gy) * RS;
                    unsafeAtomicAdd(row + ck, w2);     // ds_add_f32
                    unsafeAtomicAdd(row + ce48, w2);
                }
            }
        }
    }
    __syncthreads();

    if (tid < 512) {
        // ff_scale: 128 bins x 4 threads.
        int lb = tid >> 2, q = tid & 3;
        const float* row = acc + lb * RS;
        float raw = 0.f, effck = 0.f, effce = 0.f;
#pragma unroll
        for (int c = 0; c < 12; ++c) {
            float v = row[12 * q + c];
            raw += v;
            effck += ceilf(v * 0.125f);
        }
#pragma unroll
        for (int c = 0; c < 24; ++c) {
            effce += ceilf(row[48 + 24 * q + c] * 0.25f);
        }
        raw   += __shfl_xor(raw, 1);   raw   += __shfl_xor(raw, 2);
        effck += __shfl_xor(effck, 1); effck += __shfl_xor(effck, 2);
        effce += __shfl_xor(effce, 1); effce += __shfl_xor(effce, 2);
        if (q == 0) {
            float eff = fmaxf(effck * 8.f, effce * 4.f);
            int gx = X0 + (lb >> 3);
            int gy = Y0 + (lb & 7);
            ff_scale[gx * NBY + gy] = fmaxf(eff / fmaxf(raw, 1e-6f), 1.f);
        }
    } else if (tid < 512 + PXW * PYW) {
        // lut patch writeback (fixed-point -> f32).
        int j = tid - 512;
        unsigned v = patch[j];
        if (v != 0u) {
            int gx = X0 - 2 + j / PYW;
            int gy = Y0 - 2 + j % PYW;
            if (gx >= 0 && gx < NBX && gy >= 0 && gy < NBY)
                unsafeAtomicAdd(&lut_dem[gx * NBY + gy], (float)v * (1.f / 65536.f));
        }
    }
}

// Pass 3: per-instance gather (exact f32 weights).
__global__ void __launch_bounds__(256) area_kernel(
        const float* __restrict__ pos,
        const int* __restrict__ luts,
        const int* __restrict__ ffs,
        const float* __restrict__ lut_dem,
        const float* __restrict__ ff_scale,
        float* __restrict__ out) {
    int i = blockIdx.x * blockDim.x + threadIdx.x;
    if (i >= N_INST) return;
    bool is_lut = luts[i] > 0;
    bool is_ff  = (ffs[i] > 0) && !is_lut;
    if (!is_lut && !is_ff) { out[i] = 0.f; return; }

    float px = pos[2 * i], py = pos[2 * i + 1];
    int lox, loy;
    float wx[K], wy[K];
    axis_weights4(px, NBX, lox, wx);
    axis_weights4(py, NBY, loy, wy);

    const float* tbl = is_lut ? lut_dem : ff_scale;
    float acc = 0.f;
#pragma unroll
    for (int kx = 0; kx < K; ++kx) {
        int gx = min(max(lox + kx, 0), NBX - 1);
#pragma unroll
        for (int ky = 0; ky < K; ++ky) {
            int gy = min(max(loy + ky, 0), NBY - 1);
            float w2 = wx[kx] * wy[ky];
            float v = tbl[gx * NBY + gy];
            float sc = is_lut ? fmaxf(v * 0.0625f, 1.f) : v;
            acc += w2 * sc;
        }
    }
    out[i] = acc;
}

extern "C" void kernel_launch(void* const* d_in, const int* in_sizes, int n_in,
                              void* d_out, int out_size, void* d_ws, size_t ws_size,
                              hipStream_t stream) {
    const float* pos  = (const float*)d_in[0];
    const int*   luts = (const int*)d_in[1];
    const int*   ffs  = (const int*)d_in[2];
    const int*   ctrl = (const int*)d_in[3];
    float* out = (float*)d_out;

    // ws: lut_cur[NFT*16] | ff_cur[NFT*16] | lut_dem[NB] | ff_scale[NB]
    //     | lutb[NFT*CAPL] float2 (8MB) | ffb[NFT*CAPF] uint4 (8MB)
    int*    lut_cur  = (int*)d_ws;
    int*    ff_cur   = lut_cur + NFT * CSTRIDE;
    float*  lut_dem  = (float*)(ff_cur + NFT * CSTRIDE);
    float*  ff_scale = lut_dem + NB;
    float2* lutb     = (float2*)(ff_scale + NB);
    uint4*  ffb      = (uint4*)(lutb + (size_t)NFT * CAPL);   // 16B-aligned

    // Zero cursors + lut_dem (contiguous). ff_scale fully written by tile_kernel.
    hipMemsetAsync(d_ws, 0, (size_t)(2 * NFT * CSTRIDE + NB) * sizeof(int), stream);

    dim3 blk(256);
    dim3 grdI((N_INST + 255) / 256);

    classify_kernel<<<grdI, blk, 0, stream>>>(pos, luts, ffs, ctrl,
                                              lut_cur, ff_cur, lutb, ffb);
    tile_kernel<<<NFT, dim3(1024), 0, stream>>>(lutb, ffb, lut_cur, ff_cur,
                                                lut_dem, ff_scale);
    area_kernel<<<grdI, blk, 0, stream>>>(pos, luts, ffs, lut_dem, ff_scale, out);
}

// Round 13
// 133.687 us; speedup vs baseline: 4.8682x; 1.0127x over previous
//
#include <hip/hip_runtime.h>

#define N_INST   1000000
#define NBX      512
#define NBY      512
#define NB       (NBX * NBY)
#define NUM_CKSR 48
#define NUM_CE   96
#define K        4          // w[4] of the reference 5-tap is identically 0 (half = 1.5 exactly)

// Tiling: 16x8-bin tiles; entries carry RAW (px,py), weights recomputed at use (R12).
// Each tile bucket is split into SUB=8 sub-buckets keyed by blockIdx&7 (XCD proxy) so
// every bucket line has ONE writer-XCD -> no cross-XCD line ping-pong (R12: 54MB write
// for a 12MB payload). Caps are safe regardless of the true block->XCD mapping because
// blockIdx&7 partitions blocks uniformly.
#define FTX   16
#define FTY   8
#define TGX   (NBX / FTX)   // 32
#define TGY   (NBY / FTY)   // 64
#define NFT   (TGX * TGY)   // 2048
#define SUB   8
#define CAPL  96            // per sub-bucket; lut mean 43.6, +~6 sigma
#define CAPF  48            // per sub-bucket; ff mean 14.3 (dup 1.633), +~8 sigma
#define RS    145           // 48 ck + 96 ce + pad (odd stride, conflict-free)
#define ACCW  (FTX * FTY * RS)      // 18560 words
#define PXW   20            // lut patch: x in [X0-2, X0+17]
#define PYW   12            // y in [Y0-2, Y0+9]

#define CSTRIDE 16          // one cursor per 64B line (R5 lesson)

// Constants folded in DOUBLE then rounded once to f32 (matches JAX): half = 1.5f exactly.
#define KHALF  ((float)(2.5 * 0.6))
#define KDENOM ((float)(0.6 * 1.4142135623730951))

// 4-tap truncated-Gaussian weights; 5 shared erf edges, bit-identical to reference.
__device__ __forceinline__ void axis_weights4(float pos, int nbins, int& lo_out, float w[K]) {
    float wlo = pos - KHALF;
    float whi = pos + KHALF;
    int lo_bin = (int)floorf(wlo);
    lo_out = lo_bin;
    float phi[K + 1];
#pragma unroll
    for (int k = 0; k <= K; ++k) {
        float e = (float)(lo_bin + k);
        float ec = fminf(fmaxf(e, wlo), whi);
        phi[k] = 0.5f * (1.f + erff((ec - pos) / KDENOM));
    }
    float wsum = 0.f;
#pragma unroll
    for (int k = 0; k < K; ++k) {
        int b = lo_bin + k;
        float ww = phi[k + 1] - phi[k];
        if (b < 0 || b >= nbins) ww = 0.f;
        w[k] = ww;
        wsum += ww;
    }
    float d = wsum + 1e-12f;
#pragma unroll
    for (int k = 0; k < K; ++k) w[k] = w[k] / d;   // division, as in reference
}

// Pass 1: NO erf. lut -> float2(px,py) to center tile's sub-bucket; ff -> 16B entry to
// all dilated tiles' sub-buckets. Sub-bucket = blockIdx&7.
__global__ void __launch_bounds__(256) classify_kernel(
        const float* __restrict__ pos,
        const int* __restrict__ luts,
        const int* __restrict__ ffs,
        const int* __restrict__ ctrl,
        int* __restrict__ lut_cur,        // [NFT*SUB*CSTRIDE] zeroed
        int* __restrict__ ff_cur,         // [NFT*SUB*CSTRIDE] zeroed
        float2* __restrict__ lutb,        // [NFT][SUB][CAPL]
        uint4* __restrict__ ffb) {        // [NFT][SUB][CAPF]
    int i = blockIdx.x * blockDim.x + threadIdx.x;
    if (i >= N_INST) return;
    int sb = blockIdx.x & (SUB - 1);
    bool is_lut = luts[i] > 0;
    bool is_ff  = !is_lut && (ffs[i] > 0);
    if (!is_lut && !is_ff) return;

    float px = pos[2 * i], py = pos[2 * i + 1];

    if (is_lut) {
        int t = (((int)px) >> 4) * TGY + (((int)py) >> 3);
        int sbk = t * SUB + sb;
        int slot = atomicAdd(&lut_cur[sbk * CSTRIDE], 1);
        if (slot < CAPL) lutb[(size_t)sbk * CAPL + slot] = make_float2(px, py);
        return;
    }

    unsigned meta = (unsigned)ctrl[2 * i] | (((unsigned)ctrl[2 * i + 1] + 48u) << 8);
    uint4 entry = make_uint4(__float_as_uint(px), __float_as_uint(py), meta, 0u);
    int lox = (int)floorf(px - KHALF);
    int loy = (int)floorf(py - KHALF);
    int tx0 = max(lox, 0) >> 4, tx1 = min(lox + 3, NBX - 1) >> 4;
    int ty0 = max(loy, 0) >> 3, ty1 = min(loy + 3, NBY - 1) >> 3;
    for (int tx = tx0; tx <= tx1; ++tx) {
        for (int ty = ty0; ty <= ty1; ++ty) {
            int sbk = (tx * TGY + ty) * SUB + sb;
            int slot = atomicAdd(&ff_cur[sbk * CSTRIDE], 1);
            if (slot < CAPF) ffb[(size_t)sbk * CAPF + slot] = entry;
        }
    }
}

// Pass 2: weights recomputed here. Sub-buckets flattened via small LDS prefix so the
// entry loops stay single-pass. Native LDS atomics only.
__global__ void __launch_bounds__(1024) tile_kernel(
        const float2* __restrict__ lutb,
        const uint4* __restrict__ ffb,
        const int* __restrict__ lut_cur,
        const int* __restrict__ ff_cur,
        float* __restrict__ lut_dem,
        float* __restrict__ ff_scale) {
    __shared__ float acc[ACCW];            // ff channel rows
    __shared__ unsigned patch[PXW * PYW];  // lut demand, fixed-point 2^16 (ds_add_u32)
    __shared__ int lpre[SUB + 1], fpre[SUB + 1];
    int t = blockIdx.x;
    int X0 = (t / TGY) * FTX;
    int Y0 = (t % TGY) * FTY;
    int tid = threadIdx.x;

    for (int j = tid; j < ACCW; j += 1024) acc[j] = 0.f;
    if (tid < PXW * PYW) patch[tid] = 0u;
    if (tid == 0) {
        int s = 0; lpre[0] = 0;
        for (int c = 0; c < SUB; ++c) { s += min(lut_cur[(t * SUB + c) * CSTRIDE], CAPL); lpre[c + 1] = s; }
    } else if (tid == 1) {
        int s = 0; fpre[0] = 0;
        for (int c = 0; c < SUB; ++c) { s += min(ff_cur[(t * SUB + c) * CSTRIDE], CAPF); fpre[c + 1] = s; }
    }
    __syncthreads();

    // LUT entries: recompute exact weights, 16 unconditional integer patch adds.
    int ltot = lpre[SUB];
    for (int e = tid; e < ltot; e += 1024) {
        int c = 0;
#pragma unroll
        for (int k = 1; k < SUB; ++k) c += (e >= lpre[k]);
        float2 p = lutb[((size_t)t * SUB + c) * CAPL + (e - lpre[c])];
        int lox, loy;
        float wx[K], wy[K];
        axis_weights4(p.x, NBX, lox, wx);
        axis_weights4(p.y, NBY, loy, wy);
        int base = (lox - (X0 - 2)) * PYW + (loy - (Y0 - 2));   // rx in [0,16], ry in [0,8]
#pragma unroll
        for (int kx = 0; kx < K; ++kx) {
            float wv = wx[kx] * 65536.f;
            int rb = base + kx * PYW;
#pragma unroll
            for (int ky = 0; ky < K; ++ky)
                atomicAdd(&patch[rb + ky], (unsigned)rintf(wv * wy[ky]));   // ds_add_u32
        }
    }

    // FF entries: recompute exact f32 weights, predicated interior ds_add_f32.
    int ftot = fpre[SUB];
    for (int e = tid; e < ftot; e += 1024) {
        int c = 0;
#pragma unroll
        for (int k = 1; k < SUB; ++k) c += (e >= fpre[k]);
        uint4 a = ffb[((size_t)t * SUB + c) * CAPF + (e - fpre[c])];
        float px = __uint_as_float(a.x);
        float py = __uint_as_float(a.y);
        int ck   = (int)(a.z & 255u);
        int ce48 = (int)((a.z >> 8) & 255u);
        int lox, loy;
        float wx[K], wy[K];
        axis_weights4(px, NBX, lox, wx);
        axis_weights4(py, NBY, loy, wy);
        int cx = lox - X0, cy = loy - Y0;
#pragma unroll
        for (int kx = 0; kx < K; ++kx) {
            int gx = cx + kx;
            if ((unsigned)gx >= FTX) continue;
            float wv = wx[kx];
#pragma unroll
            for (int ky = 0; ky < K; ++ky) {
                int gy = cy + ky;
                if ((unsigned)gy >= FTY) continue;
                float w2 = wv * wy[ky];
                if (w2 != 0.f) {
                    float* row = acc + (gx * FTY + gy) * RS;
                    unsafeAtomicAdd(row + ck, w2);     // ds_add_f32
                    unsafeAtomicAdd(row + ce48, w2);
                }
            }
        }
    }
    __syncthreads();

    if (tid < 512) {
        // ff_scale: 128 bins x 4 threads.
        int lb = tid >> 2, q = tid & 3;
        const float* row = acc + lb * RS;
        float raw = 0.f, effck = 0.f, effce = 0.f;
#pragma unroll
        for (int c = 0; c < 12; ++c) {
            float v = row[12 * q + c];
            raw += v;
            effck += ceilf(v * 0.125f);
        }
#pragma unroll
        for (int c = 0; c < 24; ++c) {
            effce += ceilf(row[48 + 24 * q + c] * 0.25f);
        }
        raw   += __shfl_xor(raw, 1);   raw   += __shfl_xor(raw, 2);
        effck += __shfl_xor(effck, 1); effck += __shfl_xor(effck, 2);
        effce += __shfl_xor(effce, 1); effce += __shfl_xor(effce, 2);
        if (q == 0) {
            float eff = fmaxf(effck * 8.f, effce * 4.f);
            int gx = X0 + (lb >> 3);
            int gy = Y0 + (lb & 7);
            ff_scale[gx * NBY + gy] = fmaxf(eff / fmaxf(raw, 1e-6f), 1.f);
        }
    } else if (tid < 512 + PXW * PYW) {
        // lut patch writeback (fixed-point -> f32).
        int j = tid - 512;
        unsigned v = patch[j];
        if (v != 0u) {
            int gx = X0 - 2 + j / PYW;
            int gy = Y0 - 2 + j % PYW;
            if (gx >= 0 && gx < NBX && gy >= 0 && gy < NBY)
                unsafeAtomicAdd(&lut_dem[gx * NBY + gy], (float)v * (1.f / 65536.f));
        }
    }
}

// Pass 3: per-instance gather (exact f32 weights).
__global__ void __launch_bounds__(256) area_kernel(
        const float* __restrict__ pos,
        const int* __restrict__ luts,
        const int* __restrict__ ffs,
        const float* __restrict__ lut_dem,
        const float* __restrict__ ff_scale,
        float* __restrict__ out) {
    int i = blockIdx.x * blockDim.x + threadIdx.x;
    if (i >= N_INST) return;
    bool is_lut = luts[i] > 0;
    bool is_ff  = (ffs[i] > 0) && !is_lut;
    if (!is_lut && !is_ff) { out[i] = 0.f; return; }

    float px = pos[2 * i], py = pos[2 * i + 1];
    int lox, loy;
    float wx[K], wy[K];
    axis_weights4(px, NBX, lox, wx);
    axis_weights4(py, NBY, loy, wy);

    const float* tbl = is_lut ? lut_dem : ff_scale;
    float acc = 0.f;
#pragma unroll
    for (int kx = 0; kx < K; ++kx) {
        int gx = min(max(lox + kx, 0), NBX - 1);
#pragma unroll
        for (int ky = 0; ky < K; ++ky) {
            int gy = min(max(loy + ky, 0), NBY - 1);
            float w2 = wx[kx] * wy[ky];
            float v = tbl[gx * NBY + gy];
            float sc = is_lut ? fmaxf(v * 0.0625f, 1.f) : v;
            acc += w2 * sc;
        }
    }
    out[i] = acc;
}

extern "C" void kernel_launch(void* const* d_in, const int* in_sizes, int n_in,
                              void* d_out, int out_size, void* d_ws, size_t ws_size,
                              hipStream_t stream) {
    const float* pos  = (const float*)d_in[0];
    const int*   luts = (const int*)d_in[1];
    const int*   ffs  = (const int*)d_in[2];
    const int*   ctrl = (const int*)d_in[3];
    float* out = (float*)d_out;

    // ws: lut_cur[NFT*SUB*16] (1MB) | ff_cur[NFT*SUB*16] (1MB) | lut_dem[NB] | ff_scale[NB]
    //     | lutb[NFT*SUB*CAPL] float2 (12.6MB) | ffb[NFT*SUB*CAPF] uint4 (12.6MB)
    int*    lut_cur  = (int*)d_ws;
    int*    ff_cur   = lut_cur + NFT * SUB * CSTRIDE;
    float*  lut_dem  = (float*)(ff_cur + NFT * SUB * CSTRIDE);
    float*  ff_scale = lut_dem + NB;
    float2* lutb     = (float2*)(ff_scale + NB);
    uint4*  ffb      = (uint4*)(lutb + (size_t)NFT * SUB * CAPL);   // 16B-aligned

    // Zero cursors + lut_dem (contiguous ~3MB). ff_scale fully written by tile_kernel.
    hipMemsetAsync(d_ws, 0, (size_t)(2 * NFT * SUB * CSTRIDE + NB) * sizeof(int), stream);

    dim3 blk(256);
    dim3 grdI((N_INST + 255) / 256);

    classify_kernel<<<grdI, blk, 0, stream>>>(pos, luts, ffs, ctrl,
                                              lut_cur, ff_cur, lutb, ffb);
    tile_kernel<<<NFT, dim3(1024), 0, stream>>>(lutb, ffb, lut_cur, ff_cur,
                                                lut_dem, ff_scale);
    area_kernel<<<grdI, blk, 0, stream>>>(pos, luts, ffs, lut_dem, ff_scale, out);
}

// Round 15
// 132.589 us; speedup vs baseline: 4.9085x; 1.0083x over previous
//
#include <hip/hip_runtime.h>

#define N_INST   1000000
#define NBX      512
#define NBY      512
#define NB       (NBX * NBY)
#define NUM_CKSR 48
#define NUM_CE   96
#define K        4          // w[4] of the reference 5-tap is identically 0 (half = 1.5 exactly)

// erf ONCE per instance (classify). lut weights u10 (no ceil on lut path -> safe, R11).
// ff weights EXACT f32 end-to-end: ceil(c/8) is sharp at 0+ (R9) AND scale=eff/raw is a
// ratio of weights, so tiny weights need full relative accuracy (R14 failed with min-1).
#define FTX   16
#define FTY   8
#define TGX   (NBX / FTX)   // 32
#define TGY   (NBY / FTY)   // 64
#define NFT   (TGX * TGY)   // 2048
#define SUB   8             // sub-buckets by blockIdx&7 (R13: kills cross-XCD line ping-pong)
#define CAPL  96            // per sub-bucket; lut mean 43.6
#define CAPF  48            // per sub-bucket; ff mean 14.3 (dup 1.633)
#define RS    145           // 48 ck + 96 ce + pad (odd stride, conflict-free)
#define ACCW  (FTX * FTY * RS)      // 18560 words
#define PXW   20            // lut patch: x in [X0-2, X0+17]
#define PYW   12            // y in [Y0-2, Y0+9]

#define CSTRIDE 16          // one cursor per 64B line (R5 lesson)

// Constants folded in DOUBLE then rounded once to f32 (matches JAX): half = 1.5f exactly.
#define KHALF  ((float)(2.5 * 0.6))
#define KDENOM ((float)(0.6 * 1.4142135623730951))

__device__ __forceinline__ void axis_weights4(float pos, int nbins, int& lo_out, float w[K]) {
    float wlo = pos - KHALF;
    float whi = pos + KHALF;
    int lo_bin = (int)floorf(wlo);
    lo_out = lo_bin;
    float phi[K + 1];
#pragma unroll
    for (int k = 0; k <= K; ++k) {
        float e = (float)(lo_bin + k);
        float ec = fminf(fmaxf(e, wlo), whi);
        phi[k] = 0.5f * (1.f + erff((ec - pos) / KDENOM));
    }
    float wsum = 0.f;
#pragma unroll
    for (int k = 0; k < K; ++k) {
        int b = lo_bin + k;
        float ww = phi[k + 1] - phi[k];
        if (b < 0 || b >= nbins) ww = 0.f;
        w[k] = ww;
        wsum += ww;
    }
    float d = wsum + 1e-12f;
#pragma unroll
    for (int k = 0; k < K; ++k) w[k] = w[k] / d;   // division, as in reference
}

__device__ __forceinline__ unsigned q10(float w) {   // plain u10 (lut path only)
    return min(1023u, (unsigned)rintf(w * 1024.f));
}

// Pass 1: the ONLY erf. lut -> u10 bucket entry + instw. ff -> f32 SoA bucket entries
// + linear instlo/instfx/instfy for area.
__global__ void __launch_bounds__(256) classify_kernel(
        const float* __restrict__ pos,
        const int* __restrict__ luts,
        const int* __restrict__ ffs,
        const int* __restrict__ ctrl,
        int* __restrict__ lut_cur,        // [NFT*SUB*CSTRIDE] zeroed
        int* __restrict__ ff_cur,         // [NFT*SUB*CSTRIDE] zeroed
        uint4* __restrict__ lutb,         // [NFT][SUB][CAPL]
        float4* __restrict__ ffwx,        // [NFT*SUB*CAPF]
        float4* __restrict__ ffwy,
        unsigned* __restrict__ ffmeta,
        uint4* __restrict__ instw,        // [N_INST] (lut only)
        int* __restrict__ instlo,         // [N_INST] (ff only)
        float4* __restrict__ instfx,      // [N_INST] (ff only)
        float4* __restrict__ instfy) {    // [N_INST] (ff only)
    int i = blockIdx.x * blockDim.x + threadIdx.x;
    if (i >= N_INST) return;
    int sb = blockIdx.x & (SUB - 1);
    bool is_lut = luts[i] > 0;
    bool is_ff  = !is_lut && (ffs[i] > 0);
    if (!is_lut && !is_ff) return;

    float px = pos[2 * i], py = pos[2 * i + 1];
    int lox, loy;
    float wx[K], wy[K];
    axis_weights4(px, NBX, lox, wx);
    axis_weights4(py, NBY, loy, wy);

    if (is_lut) {
        unsigned qx[4] = { q10(wx[0]), q10(wx[1]), q10(wx[2]), q10(wx[3]) };
        unsigned qy[4] = { q10(wy[0]), q10(wy[1]), q10(wy[2]), q10(wy[3]) };
        uint4 e;
        e.x = qx[0] | (qx[1] << 10) | (qx[2] << 20);
        e.y = qx[3] | (qy[0] << 10) | (qy[1] << 20);
        e.z = qy[2] | (qy[3] << 10);
        uint4 iw = e;
        iw.w = (unsigned)(lox + 2) | ((unsigned)(loy + 2) << 10);
        instw[i] = iw;
        int tx = ((int)px) >> 4, ty = ((int)py) >> 3;
        unsigned rx = (unsigned)(lox - tx * FTX + 2);   // [0,16]
        unsigned ry = (unsigned)(loy - ty * FTY + 2);   // [0,8]
        e.w = rx | (ry << 5);
        int sbk = (tx * TGY + ty) * SUB + sb;
        int slot = atomicAdd(&lut_cur[sbk * CSTRIDE], 1);
        if (slot < CAPL) lutb[(size_t)sbk * CAPL + slot] = e;
        return;
    }

    float4 w1 = make_float4(wx[0], wx[1], wx[2], wx[3]);
    float4 w2 = make_float4(wy[0], wy[1], wy[2], wy[3]);
    instlo[i] = (lox + 2) | ((loy + 2) << 10);
    instfx[i] = w1;
    instfy[i] = w2;

    unsigned ck   = (unsigned)ctrl[2 * i];
    unsigned ce48 = 48u + (unsigned)ctrl[2 * i + 1];
    int tx0 = max(lox, 0) >> 4, tx1 = min(lox + 3, NBX - 1) >> 4;
    int ty0 = max(loy, 0) >> 3, ty1 = min(loy + 3, NBY - 1) >> 3;
    for (int tx = tx0; tx <= tx1; ++tx) {
        for (int ty = ty0; ty <= ty1; ++ty) {
            unsigned cx = (unsigned)(lox - tx * FTX + 4);   // [1,19]
            unsigned cy = (unsigned)(loy - ty * FTY + 4);   // [1,11]
            int sbk = (tx * TGY + ty) * SUB + sb;
            int slot = atomicAdd(&ff_cur[sbk * CSTRIDE], 1);
            if (slot < CAPF) {
                size_t idx = (size_t)sbk * CAPF + slot;
                ffwx[idx] = w1;
                ffwy[idx] = w2;
                ffmeta[idx] = ck | (ce48 << 6) | (cx << 14) | (cy << 19);
            }
        }
    }
}

// Pass 2: pure decode + native LDS atomics (no erf). Lut: integer qx*qy patch adds
// (max sum ~8.1e8 < 2^32), 2^-20 scale at writeback. FF: exact f32 ds_add_f32.
__global__ void __launch_bounds__(1024) tile_kernel(
        const uint4* __restrict__ lutb,
        const float4* __restrict__ ffwx,
        const float4* __restrict__ ffwy,
        const unsigned* __restrict__ ffmeta,
        const int* __restrict__ lut_cur,
        const int* __restrict__ ff_cur,
        float* __restrict__ lut_dem,
        float* __restrict__ ff_scale) {
    __shared__ float acc[ACCW];            // ff channel rows
    __shared__ unsigned patch[PXW * PYW];  // lut demand, fixed-point 2^20
    __shared__ int lpre[SUB + 1], fpre[SUB + 1];
    int t = blockIdx.x;
    int X0 = (t / TGY) * FTX;
    int Y0 = (t % TGY) * FTY;
    int tid = threadIdx.x;

    for (int j = tid; j < ACCW; j += 1024) acc[j] = 0.f;
    if (tid < PXW * PYW) patch[tid] = 0u;
    if (tid == 0) {
        int s = 0; lpre[0] = 0;
        for (int c = 0; c < SUB; ++c) { s += min(lut_cur[(t * SUB + c) * CSTRIDE], CAPL); lpre[c + 1] = s; }
    } else if (tid == 1) {
        int s = 0; fpre[0] = 0;
        for (int c = 0; c < SUB; ++c) { s += min(ff_cur[(t * SUB + c) * CSTRIDE], CAPF); fpre[c + 1] = s; }
    }
    __syncthreads();

    int ltot = lpre[SUB];
    for (int e = tid; e < ltot; e += 1024) {
        int c = 0;
#pragma unroll
        for (int k = 1; k < SUB; ++k) c += (e >= lpre[k]);
        uint4 a = lutb[((size_t)t * SUB + c) * CAPL + (e - lpre[c])];
        unsigned qx[4] = { a.x & 1023u, (a.x >> 10) & 1023u, (a.x >> 20) & 1023u, a.y & 1023u };
        unsigned qy[4] = { (a.y >> 10) & 1023u, (a.y >> 20) & 1023u, a.z & 1023u, (a.z >> 10) & 1023u };
        int base = (int)(a.w & 31u) * PYW + (int)((a.w >> 5) & 15u);
#pragma unroll
        for (int kx = 0; kx < K; ++kx) {
            int rb = base + kx * PYW;
#pragma unroll
            for (int ky = 0; ky < K; ++ky)
                atomicAdd(&patch[rb + ky], qx[kx] * qy[ky]);   // ds_add_u32
        }
    }

    int ftot = fpre[SUB];
    for (int e = tid; e < ftot; e += 1024) {
        int c = 0;
#pragma unroll
        for (int k = 1; k < SUB; ++k) c += (e >= fpre[k]);
        size_t idx = ((size_t)t * SUB + c) * CAPF + (e - fpre[c]);
        float4 a = ffwx[idx];
        float4 b = ffwy[idx];
        unsigned m = ffmeta[idx];
        float fx[4] = { a.x, a.y, a.z, a.w };
        float fy[4] = { b.x, b.y, b.z, b.w };
        int ck   = (int)(m & 63u);
        int ce48 = (int)((m >> 6) & 255u);
        int cx   = (int)((m >> 14) & 31u) - 4;
        int cy   = (int)((m >> 19) & 15u) - 4;
#pragma unroll
        for (int kx = 0; kx < K; ++kx) {
            int gx = cx + kx;
            if ((unsigned)gx >= FTX) continue;
            float wv = fx[kx];
#pragma unroll
            for (int ky = 0; ky < K; ++ky) {
                int gy = cy + ky;
                if ((unsigned)gy >= FTY) continue;
                float w2 = wv * fy[ky];
                if (w2 != 0.f) {
                    float* row = acc + (gx * FTY + gy) * RS;
                    unsafeAtomicAdd(row + ck, w2);     // ds_add_f32
                    unsafeAtomicAdd(row + ce48, w2);
                }
            }
        }
    }
    __syncthreads();

    if (tid < 512) {
        int lb = tid >> 2, q = tid & 3;
        const float* row = acc + lb * RS;
        float raw = 0.f, effck = 0.f, effce = 0.f;
#pragma unroll
        for (int c = 0; c < 12; ++c) {
            float v = row[12 * q + c];
            raw += v;
            effck += ceilf(v * 0.125f);
        }
#pragma unroll
        for (int c = 0; c < 24; ++c) {
            effce += ceilf(row[48 + 24 * q + c] * 0.25f);
        }
        raw   += __shfl_xor(raw, 1);   raw   += __shfl_xor(raw, 2);
        effck += __shfl_xor(effck, 1); effck += __shfl_xor(effck, 2);
        effce += __shfl_xor(effce, 1); effce += __shfl_xor(effce, 2);
        if (q == 0) {
            float eff = fmaxf(effck * 8.f, effce * 4.f);
            int gx = X0 + (lb >> 3);
            int gy = Y0 + (lb & 7);
            ff_scale[gx * NBY + gy] = fmaxf(eff / fmaxf(raw, 1e-6f), 1.f);
        }
    } else if (tid < 512 + PXW * PYW) {
        int j = tid - 512;
        unsigned v = patch[j];
        if (v != 0u) {
            int gx = X0 - 2 + j / PYW;
            int gy = Y0 - 2 + j % PYW;
            if (gx >= 0 && gx < NBX && gy >= 0 && gy < NBY)
                unsafeAtomicAdd(&lut_dem[gx * NBY + gy], (float)v * (1.f / 1048576.f));
        }
    }
}

// Pass 3: per-instance gather from stored weights (no erf). lut: u10; ff: exact f32.
__global__ void __launch_bounds__(256) area_kernel(
        const int* __restrict__ luts,
        const int* __restrict__ ffs,
        const uint4* __restrict__ instw,
        const int* __restrict__ instlo,
        const float4* __restrict__ instfx,
        const float4* __restrict__ instfy,
        const float* __restrict__ lut_dem,
        const float* __restrict__ ff_scale,
        float* __restrict__ out) {
    int i = blockIdx.x * blockDim.x + threadIdx.x;
    if (i >= N_INST) return;
    bool is_lut = luts[i] > 0;
    bool is_ff  = (ffs[i] > 0) && !is_lut;
    if (!is_lut && !is_ff) { out[i] = 0.f; return; }

    float acc = 0.f;
    if (is_lut) {
        uint4 a = instw[i];
        unsigned qx[4] = { a.x & 1023u, (a.x >> 10) & 1023u, (a.x >> 20) & 1023u, a.y & 1023u };
        unsigned qy[4] = { (a.y >> 10) & 1023u, (a.y >> 20) & 1023u, a.z & 1023u, (a.z >> 10) & 1023u };
        int lox = (int)(a.w & 1023u) - 2;
        int loy = (int)((a.w >> 10) & 1023u) - 2;
#pragma unroll
        for (int kx = 0; kx < K; ++kx) {
            int gx = min(max(lox + kx, 0), NBX - 1);
#pragma unroll
            for (int ky = 0; ky < K; ++ky) {
                int gy = min(max(loy + ky, 0), NBY - 1);
                float w2 = (float)(qx[kx] * qy[ky]) * (1.f / 1048576.f);
                float v = lut_dem[gx * NBY + gy];
                acc += w2 * fmaxf(v * 0.0625f, 1.f);
            }
        }
    } else {
        int lo = instlo[i];
        int lox = (lo & 1023) - 2;
        int loy = ((lo >> 10) & 1023) - 2;
        float4 a = instfx[i];
        float4 b = instfy[i];
        float fx[4] = { a.x, a.y, a.z, a.w };
        float fy[4] = { b.x, b.y, b.z, b.w };
#pragma unroll
        for (int kx = 0; kx < K; ++kx) {
            int gx = min(max(lox + kx, 0), NBX - 1);
#pragma unroll
            for (int ky = 0; ky < K; ++ky) {
                int gy = min(max(loy + ky, 0), NBY - 1);
                acc += fx[kx] * fy[ky] * ff_scale[gx * NBY + gy];
            }
        }
    }
    out[i] = acc;
}

extern "C" void kernel_launch(void* const* d_in, const int* in_sizes, int n_in,
                              void* d_out, int out_size, void* d_ws, size_t ws_size,
                              hipStream_t stream) {
    const float* pos  = (const float*)d_in[0];
    const int*   luts = (const int*)d_in[1];
    const int*   ffs  = (const int*)d_in[2];
    const int*   ctrl = (const int*)d_in[3];
    float* out = (float*)d_out;

    // ws: lut_cur (1MB) | ff_cur (1MB) | lut_dem (1MB) | ff_scale (1MB)
    //     | lutb (25.2MB) | ffwx (12.6MB) | ffwy (12.6MB) | ffmeta (3.1MB)
    //     | instw (16MB) | instlo (4MB) | instfx (16MB) | instfy (16MB)   ~110MB
    int*      lut_cur  = (int*)d_ws;
    int*      ff_cur   = lut_cur + NFT * SUB * CSTRIDE;
    float*    lut_dem  = (float*)(ff_cur + NFT * SUB * CSTRIDE);
    float*    ff_scale = lut_dem + NB;
    uint4*    lutb     = (uint4*)(ff_scale + NB);
    float4*   ffwx     = (float4*)(lutb + (size_t)NFT * SUB * CAPL);
    float4*   ffwy     = ffwx + (size_t)NFT * SUB * CAPF;
    unsigned* ffmeta   = (unsigned*)(ffwy + (size_t)NFT * SUB * CAPF);
    uint4*    instw    = (uint4*)(ffmeta + (size_t)NFT * SUB * CAPF);
    int*      instlo   = (int*)(instw + N_INST);
    float4*   instfx   = (float4*)(instlo + N_INST);
    float4*   instfy   = instfx + N_INST;

    // Zero cursors + lut_dem (contiguous ~3MB). ff_scale fully written by tile_kernel.
    hipMemsetAsync(d_ws, 0, (size_t)(2 * NFT * SUB * CSTRIDE + NB) * sizeof(int), stream);

    dim3 blk(256);
    dim3 grdI((N_INST + 255) / 256);

    classify_kernel<<<grdI, blk, 0, stream>>>(pos, luts, ffs, ctrl,
                                              lut_cur, ff_cur, lutb, ffwx, ffwy, ffmeta,
                                              instw, instlo, instfx, instfy);
    tile_kernel<<<NFT, dim3(1024), 0, stream>>>(lutb, ffwx, ffwy, ffmeta,
                                                lut_cur, ff_cur, lut_dem, ff_scale);
    area_kernel<<<grdI, blk, 0, stream>>>(luts, ffs, instw, instlo, instfx, instfy,
                                          lut_dem, ff_scale, out);
}

// Round 16
// 125.235 us; speedup vs baseline: 5.1967x; 1.0587x over previous
//
#include <hip/hip_runtime.h>

#define N_INST   1000000
#define NBX      512
#define NBY      512
#define NB       (NBX * NBY)
#define NUM_CKSR 48
#define NUM_CE   96
#define K        4          // w[4] of the reference 5-tap is identically 0 (half = 1.5 exactly)

// Structure (R16): classify does erf once -> bucket entries only (no per-instance weight
// cache: storing weights through HBM cost more than recomputing, R15). tile is pure
// decode + native LDS atomics (R15). area recomputes erf from pos (R13).
// Numerics: lut path u10 quantized (no ceil -> safe, R11); ff path EXACT f32 end-to-end
// (ceil sharp at 0+ AND scale=eff/raw needs full relative accuracy of tiny weights, R9/R14).
#define FTX   16
#define FTY   8
#define TGX   (NBX / FTX)   // 32
#define TGY   (NBY / FTY)   // 64
#define NFT   (TGX * TGY)   // 2048
#define SUB   8             // sub-buckets by blockIdx&7 (R13: kills cross-XCD line ping-pong)
#define CAPL  96            // per sub-bucket; lut mean 43.6
#define CAPF  48            // per sub-bucket; ff mean 14.3 (dup 1.633)
#define RS    145           // 48 ck + 96 ce + pad (odd stride, conflict-free)
#define ACCW  (FTX * FTY * RS)      // 18560 words
#define PXW   20            // lut patch: x in [X0-2, X0+17]
#define PYW   12            // y in [Y0-2, Y0+9]

#define CSTRIDE 16          // one cursor per 64B line (R5 lesson)

// Constants folded in DOUBLE then rounded once to f32 (matches JAX): half = 1.5f exactly.
#define KHALF  ((float)(2.5 * 0.6))
#define KDENOM ((float)(0.6 * 1.4142135623730951))

__device__ __forceinline__ void axis_weights4(float pos, int nbins, int& lo_out, float w[K]) {
    float wlo = pos - KHALF;
    float whi = pos + KHALF;
    int lo_bin = (int)floorf(wlo);
    lo_out = lo_bin;
    float phi[K + 1];
#pragma unroll
    for (int k = 0; k <= K; ++k) {
        float e = (float)(lo_bin + k);
        float ec = fminf(fmaxf(e, wlo), whi);
        phi[k] = 0.5f * (1.f + erff((ec - pos) / KDENOM));
    }
    float wsum = 0.f;
#pragma unroll
    for (int k = 0; k < K; ++k) {
        int b = lo_bin + k;
        float ww = phi[k + 1] - phi[k];
        if (b < 0 || b >= nbins) ww = 0.f;
        w[k] = ww;
        wsum += ww;
    }
    float d = wsum + 1e-12f;
#pragma unroll
    for (int k = 0; k < K; ++k) w[k] = w[k] / d;   // division, as in reference
}

__device__ __forceinline__ unsigned q10(float w) {   // plain u10 (lut path only)
    return min(1023u, (unsigned)rintf(w * 1024.f));
}

// Pass 1: erf once. lut -> u10-packed 16B entry (center tile); ff -> f32 SoA entries
// (wx4/wy4/meta) to all dilated tiles.
__global__ void __launch_bounds__(256) classify_kernel(
        const float* __restrict__ pos,
        const int* __restrict__ luts,
        const int* __restrict__ ffs,
        const int* __restrict__ ctrl,
        int* __restrict__ lut_cur,        // [NFT*SUB*CSTRIDE] zeroed
        int* __restrict__ ff_cur,         // [NFT*SUB*CSTRIDE] zeroed
        uint4* __restrict__ lutb,         // [NFT][SUB][CAPL]
        float4* __restrict__ ffwx,        // [NFT*SUB*CAPF]
        float4* __restrict__ ffwy,
        unsigned* __restrict__ ffmeta) {
    int i = blockIdx.x * blockDim.x + threadIdx.x;
    if (i >= N_INST) return;
    int sb = blockIdx.x & (SUB - 1);
    bool is_lut = luts[i] > 0;
    bool is_ff  = !is_lut && (ffs[i] > 0);
    if (!is_lut && !is_ff) return;

    float px = pos[2 * i], py = pos[2 * i + 1];
    int lox, loy;
    float wx[K], wy[K];
    axis_weights4(px, NBX, lox, wx);
    axis_weights4(py, NBY, loy, wy);

    if (is_lut) {
        unsigned qx[4] = { q10(wx[0]), q10(wx[1]), q10(wx[2]), q10(wx[3]) };
        unsigned qy[4] = { q10(wy[0]), q10(wy[1]), q10(wy[2]), q10(wy[3]) };
        int tx = ((int)px) >> 4, ty = ((int)py) >> 3;
        unsigned rx = (unsigned)(lox - tx * FTX + 2);   // [0,16]
        unsigned ry = (unsigned)(loy - ty * FTY + 2);   // [0,8]
        uint4 e;
        e.x = qx[0] | (qx[1] << 10) | (qx[2] << 20);
        e.y = qx[3] | (qy[0] << 10) | (qy[1] << 20);
        e.z = qy[2] | (qy[3] << 10);
        e.w = rx | (ry << 5);
        int sbk = (tx * TGY + ty) * SUB + sb;
        int slot = atomicAdd(&lut_cur[sbk * CSTRIDE], 1);
        if (slot < CAPL) lutb[(size_t)sbk * CAPL + slot] = e;
        return;
    }

    float4 w1 = make_float4(wx[0], wx[1], wx[2], wx[3]);
    float4 w2 = make_float4(wy[0], wy[1], wy[2], wy[3]);
    unsigned ck   = (unsigned)ctrl[2 * i];
    unsigned ce48 = 48u + (unsigned)ctrl[2 * i + 1];
    int tx0 = max(lox, 0) >> 4, tx1 = min(lox + 3, NBX - 1) >> 4;
    int ty0 = max(loy, 0) >> 3, ty1 = min(loy + 3, NBY - 1) >> 3;
    for (int tx = tx0; tx <= tx1; ++tx) {
        for (int ty = ty0; ty <= ty1; ++ty) {
            unsigned cx = (unsigned)(lox - tx * FTX + 4);   // [1,19]
            unsigned cy = (unsigned)(loy - ty * FTY + 4);   // [1,11]
            int sbk = (tx * TGY + ty) * SUB + sb;
            int slot = atomicAdd(&ff_cur[sbk * CSTRIDE], 1);
            if (slot < CAPF) {
                size_t idx = (size_t)sbk * CAPF + slot;
                ffwx[idx] = w1;
                ffwy[idx] = w2;
                ffmeta[idx] = ck | (ce48 << 6) | (cx << 14) | (cy << 19);
            }
        }
    }
}

// Pass 2: pure decode + native LDS atomics (no erf). Lut: integer qx*qy patch adds
// (max sum ~8.1e8 < 2^32), 2^-20 scale at writeback. FF: exact f32 ds_add_f32.
__global__ void __launch_bounds__(1024) tile_kernel(
        const uint4* __restrict__ lutb,
        const float4* __restrict__ ffwx,
        const float4* __restrict__ ffwy,
        const unsigned* __restrict__ ffmeta,
        const int* __restrict__ lut_cur,
        const int* __restrict__ ff_cur,
        float* __restrict__ lut_dem,
        float* __restrict__ ff_scale) {
    __shared__ float acc[ACCW];            // ff channel rows
    __shared__ unsigned patch[PXW * PYW];  // lut demand, fixed-point 2^20
    __shared__ int lpre[SUB + 1], fpre[SUB + 1];
    int t = blockIdx.x;
    int X0 = (t / TGY) * FTX;
    int Y0 = (t % TGY) * FTY;
    int tid = threadIdx.x;

    for (int j = tid; j < ACCW; j += 1024) acc[j] = 0.f;
    if (tid < PXW * PYW) patch[tid] = 0u;
    if (tid == 0) {
        int s = 0; lpre[0] = 0;
        for (int c = 0; c < SUB; ++c) { s += min(lut_cur[(t * SUB + c) * CSTRIDE], CAPL); lpre[c + 1] = s; }
    } else if (tid == 1) {
        int s = 0; fpre[0] = 0;
        for (int c = 0; c < SUB; ++c) { s += min(ff_cur[(t * SUB + c) * CSTRIDE], CAPF); fpre[c + 1] = s; }
    }
    __syncthreads();

    int ltot = lpre[SUB];
    for (int e = tid; e < ltot; e += 1024) {
        int c = 0;
#pragma unroll
        for (int k = 1; k < SUB; ++k) c += (e >= lpre[k]);
        uint4 a = lutb[((size_t)t * SUB + c) * CAPL + (e - lpre[c])];
        unsigned qx[4] = { a.x & 1023u, (a.x >> 10) & 1023u, (a.x >> 20) & 1023u, a.y & 1023u };
        unsigned qy[4] = { (a.y >> 10) & 1023u, (a.y >> 20) & 1023u, a.z & 1023u, (a.z >> 10) & 1023u };
        int base = (int)(a.w & 31u) * PYW + (int)((a.w >> 5) & 15u);
#pragma unroll
        for (int kx = 0; kx < K; ++kx) {
            int rb = base + kx * PYW;
#pragma unroll
            for (int ky = 0; ky < K; ++ky)
                atomicAdd(&patch[rb + ky], qx[kx] * qy[ky]);   // ds_add_u32
        }
    }

    int ftot = fpre[SUB];
    for (int e = tid; e < ftot; e += 1024) {
        int c = 0;
#pragma unroll
        for (int k = 1; k < SUB; ++k) c += (e >= fpre[k]);
        size_t idx = ((size_t)t * SUB + c) * CAPF + (e - fpre[c]);
        float4 a = ffwx[idx];
        float4 b = ffwy[idx];
        unsigned m = ffmeta[idx];
        float fx[4] = { a.x, a.y, a.z, a.w };
        float fy[4] = { b.x, b.y, b.z, b.w };
        int ck   = (int)(m & 63u);
        int ce48 = (int)((m >> 6) & 255u);
        int cx   = (int)((m >> 14) & 31u) - 4;
        int cy   = (int)((m >> 19) & 15u) - 4;
#pragma unroll
        for (int kx = 0; kx < K; ++kx) {
            int gx = cx + kx;
            if ((unsigned)gx >= FTX) continue;
            float wv = fx[kx];
#pragma unroll
            for (int ky = 0; ky < K; ++ky) {
                int gy = cy + ky;
                if ((unsigned)gy >= FTY) continue;
                float w2 = wv * fy[ky];
                if (w2 != 0.f) {
                    float* row = acc + (gx * FTY + gy) * RS;
                    unsafeAtomicAdd(row + ck, w2);     // ds_add_f32
                    unsafeAtomicAdd(row + ce48, w2);
                }
            }
        }
    }
    __syncthreads();

    if (tid < 512) {
        int lb = tid >> 2, q = tid & 3;
        const float* row = acc + lb * RS;
        float raw = 0.f, effck = 0.f, effce = 0.f;
#pragma unroll
        for (int c = 0; c < 12; ++c) {
            float v = row[12 * q + c];
            raw += v;
            effck += ceilf(v * 0.125f);
        }
#pragma unroll
        for (int c = 0; c < 24; ++c) {
            effce += ceilf(row[48 + 24 * q + c] * 0.25f);
        }
        raw   += __shfl_xor(raw, 1);   raw   += __shfl_xor(raw, 2);
        effck += __shfl_xor(effck, 1); effck += __shfl_xor(effck, 2);
        effce += __shfl_xor(effce, 1); effce += __shfl_xor(effce, 2);
        if (q == 0) {
            float eff = fmaxf(effck * 8.f, effce * 4.f);
            int gx = X0 + (lb >> 3);
            int gy = Y0 + (lb & 7);
            ff_scale[gx * NBY + gy] = fmaxf(eff / fmaxf(raw, 1e-6f), 1.f);
        }
    } else if (tid < 512 + PXW * PYW) {
        int j = tid - 512;
        unsigned v = patch[j];
        if (v != 0u) {
            int gx = X0 - 2 + j / PYW;
            int gy = Y0 - 2 + j % PYW;
            if (gx >= 0 && gx < NBX && gy >= 0 && gy < NBY)
                unsafeAtomicAdd(&lut_dem[gx * NBY + gy], (float)v * (1.f / 1048576.f));
        }
    }
}

// Pass 3: per-instance gather; recomputes exact f32 weights from pos (cheaper than
// round-tripping a weight cache through HBM, R15).
__global__ void __launch_bounds__(256) area_kernel(
        const float* __restrict__ pos,
        const int* __restrict__ luts,
        const int* __restrict__ ffs,
        const float* __restrict__ lut_dem,
        const float* __restrict__ ff_scale,
        float* __restrict__ out) {
    int i = blockIdx.x * blockDim.x + threadIdx.x;
    if (i >= N_INST) return;
    bool is_lut = luts[i] > 0;
    bool is_ff  = (ffs[i] > 0) && !is_lut;
    if (!is_lut && !is_ff) { out[i] = 0.f; return; }

    float px = pos[2 * i], py = pos[2 * i + 1];
    int lox, loy;
    float wx[K], wy[K];
    axis_weights4(px, NBX, lox, wx);
    axis_weights4(py, NBY, loy, wy);

    const float* tbl = is_lut ? lut_dem : ff_scale;
    float acc = 0.f;
#pragma unroll
    for (int kx = 0; kx < K; ++kx) {
        int gx = min(max(lox + kx, 0), NBX - 1);
#pragma unroll
        for (int ky = 0; ky < K; ++ky) {
            int gy = min(max(loy + ky, 0), NBY - 1);
            float w2 = wx[kx] * wy[ky];
            float v = tbl[gx * NBY + gy];
            float sc = is_lut ? fmaxf(v * 0.0625f, 1.f) : v;
            acc += w2 * sc;
        }
    }
    out[i] = acc;
}

extern "C" void kernel_launch(void* const* d_in, const int* in_sizes, int n_in,
                              void* d_out, int out_size, void* d_ws, size_t ws_size,
                              hipStream_t stream) {
    const float* pos  = (const float*)d_in[0];
    const int*   luts = (const int*)d_in[1];
    const int*   ffs  = (const int*)d_in[2];
    const int*   ctrl = (const int*)d_in[3];
    float* out = (float*)d_out;

    // ws: lut_cur (1MB) | ff_cur (1MB) | lut_dem (1MB) | ff_scale (1MB)
    //     | lutb (25.2MB) | ffwx (12.6MB) | ffwy (12.6MB) | ffmeta (3.1MB)   ~58MB
    int*      lut_cur  = (int*)d_ws;
    int*      ff_cur   = lut_cur + NFT * SUB * CSTRIDE;
    float*    lut_dem  = (float*)(ff_cur + NFT * SUB * CSTRIDE);
    float*    ff_scale = lut_dem + NB;
    uint4*    lutb     = (uint4*)(ff_scale + NB);
    float4*   ffwx     = (float4*)(lutb + (size_t)NFT * SUB * CAPL);
    float4*   ffwy     = ffwx + (size_t)NFT * SUB * CAPF;
    unsigned* ffmeta   = (unsigned*)(ffwy + (size_t)NFT * SUB * CAPF);

    // Zero cursors + lut_dem (contiguous ~3MB). ff_scale fully written by tile_kernel.
    hipMemsetAsync(d_ws, 0, (size_t)(2 * NFT * SUB * CSTRIDE + NB) * sizeof(int), stream);

    dim3 blk(256);
    dim3 grdI((N_INST + 255) / 256);

    classify_kernel<<<grdI, blk, 0, stream>>>(pos, luts, ffs, ctrl,
                                              lut_cur, ff_cur, lutb, ffwx, ffwy, ffmeta);
    tile_kernel<<<NFT, dim3(1024), 0, stream>>>(lutb, ffwx, ffwy, ffmeta,
                                                lut_cur, ff_cur, lut_dem, ff_scale);
    area_kernel<<<grdI, blk, 0, stream>>>(pos, luts, ffs, lut_dem, ff_scale, out);
}